// Round 1
// baseline (333.778 us; speedup 1.0000x reference)
//
#include <hip/hip_runtime.h>

// Problem constants (fixed by reference setup_inputs)
#define B_N 8192
#define D_N 256
#define N_N 2048
#define K_N 512
#define T_N 8

// Workspace layout (floats):
//  [0]=ju_sum  [1]=jt_sum  [2]=ortho_sq  [3]=msum
//  [16 ..)            td[B]
//  [16+B ..)          vn2[B]
//  [16+2B ..)         cb[B]   (= 1 + td - vn2)
//  [16+3B ..)         nn2[N]
//  [16+3B+N ..)       fn2[K]

__device__ __forceinline__ float wave_reduce_sum(float x) {
  #pragma unroll
  for (int off = 32; off > 0; off >>= 1) x += __shfl_down(x, off, 64);
  return x;
}

// --- per-b stats: true_dist, |vhat|^2, cb = 1 + td - vn2 -------------------
__global__ __launch_bounds__(256) void stats_b_kernel(
    const float* __restrict__ v, const float* __restrict__ vhat,
    float* __restrict__ td, float* __restrict__ vn2, float* __restrict__ cb) {
  int lane = threadIdx.x & 63;
  int row = (blockIdx.x << 2) + (threadIdx.x >> 6);
  const float4 a = *(const float4*)(vhat + (size_t)row * D_N + lane * 4);
  const float4 b = *(const float4*)(v + (size_t)row * D_N + lane * 4);
  float dx = a.x - b.x, dy = a.y - b.y, dz = a.z - b.z, dw = a.w - b.w;
  float t = dx * dx + dy * dy + dz * dz + dw * dw;
  float n = a.x * a.x + a.y * a.y + a.z * a.z + a.w * a.w;
  t = wave_reduce_sum(t);
  n = wave_reduce_sum(n);
  if (lane == 0) {
    td[row] = t;
    vn2[row] = n;
    cb[row] = 1.0f + t - n;
  }
}

// --- row squared-norms (negatives, F) --------------------------------------
__global__ __launch_bounds__(256) void rownorm_kernel(
    const float* __restrict__ src, float* __restrict__ dst) {
  int lane = threadIdx.x & 63;
  int row = (blockIdx.x << 2) + (threadIdx.x >> 6);
  const float4 a = *(const float4*)(src + (size_t)row * D_N + lane * 4);
  float n = a.x * a.x + a.y * a.y + a.z * a.z + a.w * a.w;
  n = wave_reduce_sum(n);
  if (lane == 0) dst[row] = n;
}

// --- mask sum ---------------------------------------------------------------
__global__ __launch_bounds__(256) void msum_kernel(
    const int* __restrict__ mask, float* __restrict__ acc) {
  int i = blockIdx.x * 256 + threadIdx.x;
  float m = (mask[i] != 0) ? 1.0f : 0.0f;
  m = wave_reduce_sum(m);
  __shared__ float red[4];
  if ((threadIdx.x & 63) == 0) red[threadIdx.x >> 6] = m;
  __syncthreads();
  if (threadIdx.x == 0) atomicAdd(acc, red[0] + red[1] + red[2] + red[3]);
}

// --- Ju: fused GEMM (vhat . neg^T) + clamp + masked reduce ------------------
// 64x64 output tile per block, 256 threads, 4x4 micro-tile, D chunked by 16.
__global__ __launch_bounds__(256) void ju_gemm_kernel(
    const float* __restrict__ vhat, const float* __restrict__ neg,
    const float* __restrict__ cb, const float* __restrict__ nn2,
    const int* __restrict__ mask, float* __restrict__ ju_acc) {
  __shared__ float As[16][68];  // [d][b], pad 68 keeps float4 alignment, 2-way banks
  __shared__ float Bs[16][68];  // [d][n]
  __shared__ float red[256];
  int tid = threadIdx.x;
  int tx = tid & 15, ty = tid >> 4;
  int b0 = blockIdx.y << 6, n0 = blockIdx.x << 6;
  int lrow = tid >> 2;          // 0..63
  int lc = (tid & 3) << 2;      // 0,4,8,12
  float acc[4][4] = {};
  const float* aptr = vhat + (size_t)(b0 + lrow) * D_N + lc;
  const float* bptr = neg + (size_t)(n0 + lrow) * D_N + lc;
  for (int d0 = 0; d0 < D_N; d0 += 16) {
    float4 av = *(const float4*)(aptr + d0);
    float4 bv = *(const float4*)(bptr + d0);
    __syncthreads();
    As[lc + 0][lrow] = av.x; As[lc + 1][lrow] = av.y;
    As[lc + 2][lrow] = av.z; As[lc + 3][lrow] = av.w;
    Bs[lc + 0][lrow] = bv.x; Bs[lc + 1][lrow] = bv.y;
    Bs[lc + 2][lrow] = bv.z; Bs[lc + 3][lrow] = bv.w;
    __syncthreads();
    #pragma unroll
    for (int dd = 0; dd < 16; ++dd) {
      float4 a4 = *(const float4*)&As[dd][ty << 2];
      float4 b4 = *(const float4*)&Bs[dd][tx << 2];
      float ar[4] = {a4.x, a4.y, a4.z, a4.w};
      float br[4] = {b4.x, b4.y, b4.z, b4.w};
      #pragma unroll
      for (int i = 0; i < 4; ++i)
        #pragma unroll
        for (int j = 0; j < 4; ++j)
          acc[i][j] = fmaf(ar[i], br[j], acc[i][j]);
    }
  }
  // epilogue: per = max(cb[b] + 2*s - nn2[n], 0), masked row-wise
  float bsum = 0.0f;
  #pragma unroll
  for (int i = 0; i < 4; ++i) {
    int b = b0 + (ty << 2) + i;
    float mf = (mask[b] != 0) ? 1.0f : 0.0f;
    float cbi = cb[b];
    float rs = 0.0f;
    #pragma unroll
    for (int j = 0; j < 4; ++j) {
      int n = n0 + (tx << 2) + j;
      float val = cbi + 2.0f * acc[i][j] - nn2[n];
      rs += val > 0.0f ? val : 0.0f;
    }
    bsum += mf * rs;
  }
  __syncthreads();
  red[tid] = bsum;
  __syncthreads();
  for (int s = 128; s > 0; s >>= 1) {
    if (tid < s) red[tid] += red[tid + s];
    __syncthreads();
  }
  if (tid == 0) atomicAdd(ju_acc, red[0]);
}

// --- Jt: bottom-8-of-512 selection + 8 dots per row, one wave per b ---------
__global__ __launch_bounds__(256) void jt_kernel(
    const float* __restrict__ g, const float* __restrict__ F,
    const float* __restrict__ vhat, const float* __restrict__ td,
    const float* __restrict__ vn2, const float* __restrict__ fn2,
    const int* __restrict__ mask, float* __restrict__ jt_acc) {
  int lane = threadIdx.x & 63;
  int b = (blockIdx.x << 2) + (threadIdx.x >> 6);
  const float* grow = g + (size_t)b * K_N;
  float gv[8];
  {
    float4 g0 = *(const float4*)(grow + lane * 8);
    float4 g1 = *(const float4*)(grow + lane * 8 + 4);
    gv[0] = g0.x; gv[1] = g0.y; gv[2] = g0.z; gv[3] = g0.w;
    gv[4] = g1.x; gv[5] = g1.y; gv[6] = g1.z; gv[7] = g1.w;
  }
  unsigned used = 0;
  float sel_val[T_N];
  int sel_idx[T_N];
  for (int t = 0; t < T_N; ++t) {
    float lv = 3.0e38f;
    int lj = 0;
    #pragma unroll
    for (int j = 0; j < 8; ++j) {
      bool ok = (((used >> j) & 1u) == 0u) && (gv[j] < lv);
      lv = ok ? gv[j] : lv;
      lj = ok ? j : lj;
    }
    float rv = lv;
    int ri = lane * 8 + lj;
    #pragma unroll
    for (int off = 32; off > 0; off >>= 1) {
      float ov = __shfl_down(rv, off, 64);
      int oi = __shfl_down(ri, off, 64);
      if (ov < rv) { rv = ov; ri = oi; }
    }
    rv = __shfl(rv, 0, 64);
    ri = __shfl(ri, 0, 64);
    if ((ri >> 3) == lane) used |= 1u << (ri & 7);
    sel_val[t] = rv;
    sel_idx[t] = ri;
  }
  float gsum = 1e-10f;
  #pragma unroll
  for (int t = 0; t < T_N; ++t) gsum += sel_val[t];
  float4 vh = *(const float4*)(vhat + (size_t)b * D_N + lane * 4);
  float tdb = td[b], vnb = vn2[b];
  float jtb = 0.0f;
  #pragma unroll
  for (int t = 0; t < T_N; ++t) {
    const float* Fr = F + (size_t)sel_idx[t] * D_N;
    float4 f4 = *(const float4*)(Fr + lane * 4);
    float p = vh.x * f4.x + vh.y * f4.y + vh.z * f4.z + vh.w * f4.w;
    p = wave_reduce_sum(p);
    p = __shfl(p, 0, 64);
    float dneg = vnb - 2.0f * p + fn2[sel_idx[t]];
    float gt = sel_val[t] / gsum;
    float mt = (1.0f - gt) * (1.0f - gt);
    float cur = mt + tdb - dneg;
    jtb += cur > 0.0f ? cur : 0.0f;
  }
  if (lane == 0 && mask[b] != 0) atomicAdd(jt_acc, jtb);
}

// --- ortho: ||F F^T - I||_F^2 via 64x64 tile GEMM ---------------------------
__global__ __launch_bounds__(256) void ortho_kernel(
    const float* __restrict__ F, float* __restrict__ ortho_acc) {
  __shared__ float As[16][68];
  __shared__ float Bs[16][68];
  __shared__ float red[256];
  int tid = threadIdx.x;
  int tx = tid & 15, ty = tid >> 4;
  int i0 = blockIdx.y << 6, j0 = blockIdx.x << 6;
  int lrow = tid >> 2;
  int lc = (tid & 3) << 2;
  float acc[4][4] = {};
  const float* aptr = F + (size_t)(i0 + lrow) * D_N + lc;
  const float* bptr = F + (size_t)(j0 + lrow) * D_N + lc;
  for (int d0 = 0; d0 < D_N; d0 += 16) {
    float4 av = *(const float4*)(aptr + d0);
    float4 bv = *(const float4*)(bptr + d0);
    __syncthreads();
    As[lc + 0][lrow] = av.x; As[lc + 1][lrow] = av.y;
    As[lc + 2][lrow] = av.z; As[lc + 3][lrow] = av.w;
    Bs[lc + 0][lrow] = bv.x; Bs[lc + 1][lrow] = bv.y;
    Bs[lc + 2][lrow] = bv.z; Bs[lc + 3][lrow] = bv.w;
    __syncthreads();
    #pragma unroll
    for (int dd = 0; dd < 16; ++dd) {
      float4 a4 = *(const float4*)&As[dd][ty << 2];
      float4 b4 = *(const float4*)&Bs[dd][tx << 2];
      float ar[4] = {a4.x, a4.y, a4.z, a4.w};
      float br[4] = {b4.x, b4.y, b4.z, b4.w};
      #pragma unroll
      for (int i = 0; i < 4; ++i)
        #pragma unroll
        for (int j = 0; j < 4; ++j)
          acc[i][j] = fmaf(ar[i], br[j], acc[i][j]);
    }
  }
  float bsum = 0.0f;
  #pragma unroll
  for (int i = 0; i < 4; ++i) {
    int gi = i0 + (ty << 2) + i;
    #pragma unroll
    for (int j = 0; j < 4; ++j) {
      int gj = j0 + (tx << 2) + j;
      float s = acc[i][j] - (gi == gj ? 1.0f : 0.0f);
      bsum += s * s;
    }
  }
  __syncthreads();
  red[tid] = bsum;
  __syncthreads();
  for (int s = 128; s > 0; s >>= 1) {
    if (tid < s) red[tid] += red[tid + s];
    __syncthreads();
  }
  if (tid == 0) atomicAdd(ortho_acc, red[0]);
}

// --- finalize ---------------------------------------------------------------
__global__ void finalize_kernel(const float* __restrict__ ws, float* __restrict__ out) {
  if (threadIdx.x == 0 && blockIdx.x == 0) {
    float ju = ws[0], jt = ws[1], ortho = ws[2], ms = ws[3];
    float Ju = (ms == 0.0f) ? 0.0f : ju / ((float)N_N * ms);
    float Jt = (ms == 0.0f) ? 0.0f : jt / ms;
    out[0] = Ju + Jt + 1.0e-3f * ortho;
  }
}

extern "C" void kernel_launch(void* const* d_in, const int* in_sizes, int n_in,
                              void* d_out, int out_size, void* d_ws, size_t ws_size,
                              hipStream_t stream) {
  (void)in_sizes; (void)n_in; (void)out_size; (void)ws_size;
  const float* v    = (const float*)d_in[0];
  const float* vhat = (const float*)d_in[1];
  const float* g    = (const float*)d_in[2];
  const float* F    = (const float*)d_in[3];
  const float* neg  = (const float*)d_in[4];
  const int*   mask = (const int*)d_in[5];

  float* ws  = (float*)d_ws;
  float* acc = ws;            // [0]=ju, [1]=jt, [2]=ortho, [3]=msum
  float* td  = ws + 16;
  float* vn2 = td + B_N;
  float* cb  = vn2 + B_N;
  float* nn2 = cb + B_N;
  float* fn2 = nn2 + N_N;

  hipMemsetAsync(acc, 0, 4 * sizeof(float), stream);
  stats_b_kernel<<<B_N / 4, 256, 0, stream>>>(v, vhat, td, vn2, cb);
  rownorm_kernel<<<N_N / 4, 256, 0, stream>>>(neg, nn2);
  rownorm_kernel<<<K_N / 4, 256, 0, stream>>>(F, fn2);
  msum_kernel<<<B_N / 256, 256, 0, stream>>>(mask, acc + 3);
  ju_gemm_kernel<<<dim3(N_N / 64, B_N / 64), 256, 0, stream>>>(vhat, neg, cb, nn2, mask, acc + 0);
  jt_kernel<<<B_N / 4, 256, 0, stream>>>(g, F, vhat, td, vn2, fn2, mask, acc + 1);
  ortho_kernel<<<dim3(K_N / 64, K_N / 64), 256, 0, stream>>>(F, acc + 2);
  finalize_kernel<<<1, 64, 0, stream>>>(ws, (float*)d_out);
}

// Round 2
// 151.012 us; speedup vs baseline: 2.2103x; 2.2103x over previous
//
#include <hip/hip_runtime.h>

// Problem constants (fixed by reference setup_inputs)
#define B_N 8192
#define D_N 256
#define N_N 2048
#define K_N 512
#define T_N 8

using short8  = __attribute__((ext_vector_type(8))) short;
using floatx4 = __attribute__((ext_vector_type(4))) float;

// Workspace layout (floats):
//  [16 ..)                td[B]
//  [16+B ..)              vn2[B]
//  [16+2B ..)             cb[B]      (= 1 + td - vn2)
//  [16+3B ..)             nn2[N]
//  [16+3B+N ..)           fn2[K]
//  [16+3B+N+K ..)         jt_row[B]
//  [.. +B ..)             ju_part[1024]
//  [.. +1024 ..)          ortho_part[64]

__device__ __forceinline__ float wave_reduce_sum(float x) {
  #pragma unroll
  for (int off = 32; off > 0; off >>= 1) x += __shfl_down(x, off, 64);
  return x;
}

__device__ __forceinline__ unsigned short f2bf(float x) {
  unsigned u = __float_as_uint(x);
  unsigned r = (u + 0x7fffu + ((u >> 16) & 1u)) >> 16;
  return (unsigned short)r;
}

__device__ __forceinline__ void store_bf8(unsigned short* p, float4 a, float4 b) {
  union { unsigned short us[8]; uint4 v; } u;
  u.us[0] = f2bf(a.x); u.us[1] = f2bf(a.y); u.us[2] = f2bf(a.z); u.us[3] = f2bf(a.w);
  u.us[4] = f2bf(b.x); u.us[5] = f2bf(b.y); u.us[6] = f2bf(b.z); u.us[7] = f2bf(b.w);
  *(uint4*)p = u.v;
}

// --- per-b stats: true_dist, |vhat|^2, cb = 1 + td - vn2 -------------------
__global__ __launch_bounds__(256) void stats_b_kernel(
    const float* __restrict__ v, const float* __restrict__ vhat,
    float* __restrict__ td, float* __restrict__ vn2, float* __restrict__ cb) {
  int lane = threadIdx.x & 63;
  int row = (blockIdx.x << 2) + (threadIdx.x >> 6);
  const float4 a = *(const float4*)(vhat + (size_t)row * D_N + lane * 4);
  const float4 b = *(const float4*)(v + (size_t)row * D_N + lane * 4);
  float dx = a.x - b.x, dy = a.y - b.y, dz = a.z - b.z, dw = a.w - b.w;
  float t = dx * dx + dy * dy + dz * dz + dw * dw;
  float n = a.x * a.x + a.y * a.y + a.z * a.z + a.w * a.w;
  t = wave_reduce_sum(t);
  n = wave_reduce_sum(n);
  if (lane == 0) {
    td[row] = t;
    vn2[row] = n;
    cb[row] = 1.0f + t - n;
  }
}

// --- row squared-norms (negatives, F) --------------------------------------
__global__ __launch_bounds__(256) void rownorm_kernel(
    const float* __restrict__ src, float* __restrict__ dst) {
  int lane = threadIdx.x & 63;
  int row = (blockIdx.x << 2) + (threadIdx.x >> 6);
  const float4 a = *(const float4*)(src + (size_t)row * D_N + lane * 4);
  float n = a.x * a.x + a.y * a.y + a.z * a.z + a.w * a.w;
  n = wave_reduce_sum(n);
  if (lane == 0) dst[row] = n;
}

// --- Ju: bf16 MFMA GEMM (vhat . neg^T) + fused clamp/mask epilogue ----------
// 128x128 tile, 256 threads = 2x2 waves, each wave 4x4 grid of 16x16x32 MFMA.
// f32 -> bf16 conversion fused into LDS staging.
__global__ __launch_bounds__(256) void ju_mfma_kernel(
    const float* __restrict__ vhat, const float* __restrict__ neg,
    const float* __restrict__ cb, const float* __restrict__ nn2,
    const int* __restrict__ mask, float* __restrict__ ju_part) {
  __shared__ __align__(16) unsigned short As[128 * 32];  // [row][k] bf16, 8 KB
  __shared__ __align__(16) unsigned short Bs[128 * 32];  // 8 KB
  __shared__ float red[256];
  const int tid = threadIdx.x;
  const int lane = tid & 63;
  const int wave = tid >> 6;
  const int wx = wave & 1, wy = wave >> 1;  // wave tile: 64(m) x 64(n)
  const int b0 = blockIdx.y * 128, n0 = blockIdx.x * 128;

  // staging: thread handles rows (srow, srow+64), 8 f32 cols starting scol
  const int srow = tid >> 2;        // 0..63
  const int scol = (tid & 3) * 8;   // 0,8,16,24
  const float* aG0 = vhat + (size_t)(b0 + srow) * D_N + scol;
  const float* aG1 = vhat + (size_t)(b0 + srow + 64) * D_N + scol;
  const float* bG0 = neg + (size_t)(n0 + srow) * D_N + scol;
  const float* bG1 = neg + (size_t)(n0 + srow + 64) * D_N + scol;
  unsigned short* aS0 = As + srow * 32 + scol;
  unsigned short* aS1 = As + (srow + 64) * 32 + scol;
  unsigned short* bS0 = Bs + srow * 32 + scol;
  unsigned short* bS1 = Bs + (srow + 64) * 32 + scol;

  // MFMA fragment indices: A/B operand lane holds row (lane&15), k (lane>>4)*8..+7
  const int fr = lane & 15;
  const int fk = (lane >> 4) * 8;

  floatx4 acc[4][4];
  #pragma unroll
  for (int i = 0; i < 4; ++i)
    #pragma unroll
    for (int j = 0; j < 4; ++j)
      acc[i][j] = floatx4{0.0f, 0.0f, 0.0f, 0.0f};

  for (int k0 = 0; k0 < D_N; k0 += 32) {
    float4 a00 = *(const float4*)(aG0 + k0);
    float4 a01 = *(const float4*)(aG0 + k0 + 4);
    float4 a10 = *(const float4*)(aG1 + k0);
    float4 a11 = *(const float4*)(aG1 + k0 + 4);
    float4 c00 = *(const float4*)(bG0 + k0);
    float4 c01 = *(const float4*)(bG0 + k0 + 4);
    float4 c10 = *(const float4*)(bG1 + k0);
    float4 c11 = *(const float4*)(bG1 + k0 + 4);
    __syncthreads();
    store_bf8(aS0, a00, a01);
    store_bf8(aS1, a10, a11);
    store_bf8(bS0, c00, c01);
    store_bf8(bS1, c10, c11);
    __syncthreads();
    short8 af[4], bf[4];
    #pragma unroll
    for (int i = 0; i < 4; ++i)
      af[i] = *(const short8*)(As + (wy * 64 + i * 16 + fr) * 32 + fk);
    #pragma unroll
    for (int j = 0; j < 4; ++j)
      bf[j] = *(const short8*)(Bs + (wx * 64 + j * 16 + fr) * 32 + fk);
    #pragma unroll
    for (int i = 0; i < 4; ++i)
      #pragma unroll
      for (int j = 0; j < 4; ++j)
        acc[i][j] = __builtin_amdgcn_mfma_f32_16x16x32_bf16(af[i], bf[j], acc[i][j], 0, 0, 0);
  }

  // epilogue: C/D layout col=lane&15, row=(lane>>4)*4+reg
  float nns[4];
  #pragma unroll
  for (int j = 0; j < 4; ++j)
    nns[j] = nn2[n0 + wx * 64 + j * 16 + (lane & 15)];
  float lsum = 0.0f;
  #pragma unroll
  for (int i = 0; i < 4; ++i) {
    #pragma unroll
    for (int r = 0; r < 4; ++r) {
      int b = b0 + wy * 64 + i * 16 + (lane >> 4) * 4 + r;
      float cbb = cb[b];
      float mf = (mask[b] != 0) ? 1.0f : 0.0f;
      float rs = 0.0f;
      #pragma unroll
      for (int j = 0; j < 4; ++j) {
        float val = cbb + 2.0f * acc[i][j][r] - nns[j];
        rs += fmaxf(val, 0.0f);
      }
      lsum += mf * rs;
    }
  }
  __syncthreads();
  red[tid] = lsum;
  __syncthreads();
  for (int s = 128; s > 0; s >>= 1) {
    if (tid < s) red[tid] += red[tid + s];
    __syncthreads();
  }
  if (tid == 0) ju_part[blockIdx.y * gridDim.x + blockIdx.x] = red[0];
}

// --- Jt: bottom-8-of-512 selection + 8 dots per row, one wave per b ---------
__global__ __launch_bounds__(256) void jt_kernel(
    const float* __restrict__ g, const float* __restrict__ F,
    const float* __restrict__ vhat, const float* __restrict__ td,
    const float* __restrict__ vn2, const float* __restrict__ fn2,
    const int* __restrict__ mask, float* __restrict__ jt_row) {
  int lane = threadIdx.x & 63;
  int b = (blockIdx.x << 2) + (threadIdx.x >> 6);
  const float* grow = g + (size_t)b * K_N;
  float gv[8];
  {
    float4 g0 = *(const float4*)(grow + lane * 8);
    float4 g1 = *(const float4*)(grow + lane * 8 + 4);
    gv[0] = g0.x; gv[1] = g0.y; gv[2] = g0.z; gv[3] = g0.w;
    gv[4] = g1.x; gv[5] = g1.y; gv[6] = g1.z; gv[7] = g1.w;
  }
  unsigned used = 0;
  float sel_val[T_N];
  int sel_idx[T_N];
  for (int t = 0; t < T_N; ++t) {
    float lv = 3.0e38f;
    int lj = 0;
    #pragma unroll
    for (int j = 0; j < 8; ++j) {
      bool ok = (((used >> j) & 1u) == 0u) && (gv[j] < lv);
      lv = ok ? gv[j] : lv;
      lj = ok ? j : lj;
    }
    float rv = lv;
    int ri = lane * 8 + lj;
    #pragma unroll
    for (int off = 32; off > 0; off >>= 1) {
      float ov = __shfl_down(rv, off, 64);
      int oi = __shfl_down(ri, off, 64);
      if (ov < rv) { rv = ov; ri = oi; }
    }
    rv = __shfl(rv, 0, 64);
    ri = __shfl(ri, 0, 64);
    if ((ri >> 3) == lane) used |= 1u << (ri & 7);
    sel_val[t] = rv;
    sel_idx[t] = ri;
  }
  float gsum = 1e-10f;
  #pragma unroll
  for (int t = 0; t < T_N; ++t) gsum += sel_val[t];
  float4 vh = *(const float4*)(vhat + (size_t)b * D_N + lane * 4);
  float tdb = td[b], vnb = vn2[b];
  float jtb = 0.0f;
  #pragma unroll
  for (int t = 0; t < T_N; ++t) {
    const float* Fr = F + (size_t)sel_idx[t] * D_N;
    float4 f4 = *(const float4*)(Fr + lane * 4);
    float p = vh.x * f4.x + vh.y * f4.y + vh.z * f4.z + vh.w * f4.w;
    p = wave_reduce_sum(p);
    p = __shfl(p, 0, 64);
    float dneg = vnb - 2.0f * p + fn2[sel_idx[t]];
    float gt = sel_val[t] / gsum;
    float mt = (1.0f - gt) * (1.0f - gt);
    float cur = mt + tdb - dneg;
    jtb += cur > 0.0f ? cur : 0.0f;
  }
  if (lane == 0) jt_row[b] = jtb * ((mask[b] != 0) ? 1.0f : 0.0f);
}

// --- ortho: ||F F^T - I||_F^2 via 64x64 tile f32 GEMM, per-block partial ----
__global__ __launch_bounds__(256) void ortho_kernel(
    const float* __restrict__ F, float* __restrict__ ortho_part) {
  __shared__ float As[16][68];
  __shared__ float Bs[16][68];
  __shared__ float red[256];
  int tid = threadIdx.x;
  int tx = tid & 15, ty = tid >> 4;
  int i0 = blockIdx.y << 6, j0 = blockIdx.x << 6;
  int lrow = tid >> 2;
  int lc = (tid & 3) << 2;
  float acc[4][4] = {};
  const float* aptr = F + (size_t)(i0 + lrow) * D_N + lc;
  const float* bptr = F + (size_t)(j0 + lrow) * D_N + lc;
  for (int d0 = 0; d0 < D_N; d0 += 16) {
    float4 av = *(const float4*)(aptr + d0);
    float4 bv = *(const float4*)(bptr + d0);
    __syncthreads();
    As[lc + 0][lrow] = av.x; As[lc + 1][lrow] = av.y;
    As[lc + 2][lrow] = av.z; As[lc + 3][lrow] = av.w;
    Bs[lc + 0][lrow] = bv.x; Bs[lc + 1][lrow] = bv.y;
    Bs[lc + 2][lrow] = bv.z; Bs[lc + 3][lrow] = bv.w;
    __syncthreads();
    #pragma unroll
    for (int dd = 0; dd < 16; ++dd) {
      float4 a4 = *(const float4*)&As[dd][ty << 2];
      float4 b4 = *(const float4*)&Bs[dd][tx << 2];
      float ar[4] = {a4.x, a4.y, a4.z, a4.w};
      float br[4] = {b4.x, b4.y, b4.z, b4.w};
      #pragma unroll
      for (int i = 0; i < 4; ++i)
        #pragma unroll
        for (int j = 0; j < 4; ++j)
          acc[i][j] = fmaf(ar[i], br[j], acc[i][j]);
    }
  }
  float bsum = 0.0f;
  #pragma unroll
  for (int i = 0; i < 4; ++i) {
    int gi = i0 + (ty << 2) + i;
    #pragma unroll
    for (int j = 0; j < 4; ++j) {
      int gj = j0 + (tx << 2) + j;
      float s = acc[i][j] - (gi == gj ? 1.0f : 0.0f);
      bsum += s * s;
    }
  }
  __syncthreads();
  red[tid] = bsum;
  __syncthreads();
  for (int s = 128; s > 0; s >>= 1) {
    if (tid < s) red[tid] += red[tid + s];
    __syncthreads();
  }
  if (tid == 0) ortho_part[blockIdx.y * gridDim.x + blockIdx.x] = red[0];
}

// --- finalize: sum all partials, compute output -----------------------------
__global__ __launch_bounds__(256) void finalize_kernel(
    const float* __restrict__ jt_row, const float* __restrict__ ju_part,
    const float* __restrict__ ortho_part, const int* __restrict__ mask,
    float* __restrict__ out) {
  int tid = threadIdx.x;
  float sjt = 0.0f, sju = 0.0f, sor = 0.0f, sm = 0.0f;
  for (int i = tid; i < B_N; i += 256) {
    sjt += jt_row[i];
    sm += (mask[i] != 0) ? 1.0f : 0.0f;
  }
  for (int i = tid; i < 1024; i += 256) sju += ju_part[i];
  if (tid < 64) sor = ortho_part[tid];
  sjt = wave_reduce_sum(sjt);
  sju = wave_reduce_sum(sju);
  sor = wave_reduce_sum(sor);
  sm  = wave_reduce_sum(sm);
  __shared__ float red[4][4];
  int lane = tid & 63, w = tid >> 6;
  if (lane == 0) {
    red[w][0] = sjt; red[w][1] = sju; red[w][2] = sor; red[w][3] = sm;
  }
  __syncthreads();
  if (tid == 0) {
    float jt = red[0][0] + red[1][0] + red[2][0] + red[3][0];
    float ju = red[0][1] + red[1][1] + red[2][1] + red[3][1];
    float oo = red[0][2] + red[1][2] + red[2][2] + red[3][2];
    float ms = red[0][3] + red[1][3] + red[2][3] + red[3][3];
    float Ju = (ms == 0.0f) ? 0.0f : ju / ((float)N_N * ms);
    float Jt = (ms == 0.0f) ? 0.0f : jt / ms;
    out[0] = Ju + Jt + 1.0e-3f * oo;
  }
}

extern "C" void kernel_launch(void* const* d_in, const int* in_sizes, int n_in,
                              void* d_out, int out_size, void* d_ws, size_t ws_size,
                              hipStream_t stream) {
  (void)in_sizes; (void)n_in; (void)out_size; (void)ws_size;
  const float* v    = (const float*)d_in[0];
  const float* vhat = (const float*)d_in[1];
  const float* g    = (const float*)d_in[2];
  const float* F    = (const float*)d_in[3];
  const float* neg  = (const float*)d_in[4];
  const int*   mask = (const int*)d_in[5];

  float* ws  = (float*)d_ws;
  float* td       = ws + 16;
  float* vn2      = td + B_N;
  float* cb       = vn2 + B_N;
  float* nn2      = cb + B_N;
  float* fn2      = nn2 + N_N;
  float* jt_row   = fn2 + K_N;
  float* ju_part  = jt_row + B_N;
  float* or_part  = ju_part + 1024;

  stats_b_kernel<<<B_N / 4, 256, 0, stream>>>(v, vhat, td, vn2, cb);
  rownorm_kernel<<<N_N / 4, 256, 0, stream>>>(neg, nn2);
  rownorm_kernel<<<K_N / 4, 256, 0, stream>>>(F, fn2);
  ju_mfma_kernel<<<dim3(N_N / 128, B_N / 128), 256, 0, stream>>>(vhat, neg, cb, nn2, mask, ju_part);
  jt_kernel<<<B_N / 4, 256, 0, stream>>>(g, F, vhat, td, vn2, fn2, mask, jt_row);
  ortho_kernel<<<dim3(K_N / 64, K_N / 64), 256, 0, stream>>>(F, or_part);
  finalize_kernel<<<1, 256, 0, stream>>>(jt_row, ju_part, or_part, mask, (float*)d_out);
}

// Round 3
// 143.817 us; speedup vs baseline: 2.3209x; 1.0500x over previous
//
#include <hip/hip_runtime.h>

// Problem constants (fixed by reference setup_inputs)
#define B_N 8192
#define D_N 256
#define N_N 2048
#define K_N 512
#define T_N 8

using short8  = __attribute__((ext_vector_type(8))) short;
using floatx4 = __attribute__((ext_vector_type(4))) float;

// ---------------------------------------------------------------------------
// Workspace layout (float units):
//  td      = ws + 0        [8192]
//  vn2     = ws + 8192     [8192]
//  cb      = ws + 16384    [8192]
//  nn2     = ws + 24576    [2048]
//  fn2     = ws + 26624    [512]
//  jt_row  = ws + 27136    [8192]
//  ju_part = ws + 35328    [4096]
//  or_part = ws + 39424    [256]
//  vhat_bf = (ushort*)(ws + 39680)   [8192*256]   (16B aligned)
//  neg_bf  = vhat_bf + 8192*256      [2048*256]
// ---------------------------------------------------------------------------

__device__ __forceinline__ float wave_reduce_sum(float x) {
  #pragma unroll
  for (int off = 32; off > 0; off >>= 1) x += __shfl_down(x, off, 64);
  return x;
}

__device__ __forceinline__ unsigned int f2bf(float x) {
  unsigned u = __float_as_uint(x);
  return (u + 0x7fffu + ((u >> 16) & 1u)) >> 16;
}

__device__ __forceinline__ unsigned int pack2bf(float x, float y) {
  return f2bf(x) | (f2bf(y) << 16);
}

// async global->LDS, 16 bytes per lane; LDS dest is wave-uniform base + lane*16
__device__ __forceinline__ void gload16(const unsigned short* g, unsigned short* l) {
  __builtin_amdgcn_global_load_lds(
      (const __attribute__((address_space(1))) unsigned int*)g,
      (__attribute__((address_space(3))) unsigned int*)l, 16, 0, 0);
}

// --- prep: all row stats + f32->bf16 conversion of vhat/neg -----------------
// one row per wave; rows [0,B)=vhat(+v), [B,B+N)=neg, [B+N,B+N+K)=F
__global__ __launch_bounds__(256) void prep_kernel(
    const float* __restrict__ v, const float* __restrict__ vhat,
    const float* __restrict__ neg, const float* __restrict__ F,
    unsigned short* __restrict__ vhat_bf, unsigned short* __restrict__ neg_bf,
    float* __restrict__ td, float* __restrict__ vn2, float* __restrict__ cb,
    float* __restrict__ nn2, float* __restrict__ fn2) {
  int lane = threadIdx.x & 63;
  int row = (blockIdx.x << 2) + (threadIdx.x >> 6);
  if (row < B_N) {
    const float4 a = *(const float4*)(vhat + (size_t)row * D_N + lane * 4);
    const float4 b = *(const float4*)(v + (size_t)row * D_N + lane * 4);
    float dx = a.x - b.x, dy = a.y - b.y, dz = a.z - b.z, dw = a.w - b.w;
    float t = dx * dx + dy * dy + dz * dz + dw * dw;
    float n = a.x * a.x + a.y * a.y + a.z * a.z + a.w * a.w;
    uint2 p;
    p.x = pack2bf(a.x, a.y);
    p.y = pack2bf(a.z, a.w);
    *(uint2*)(vhat_bf + (size_t)row * D_N + lane * 4) = p;
    t = wave_reduce_sum(t);
    n = wave_reduce_sum(n);
    if (lane == 0) {
      td[row] = t;
      vn2[row] = n;
      cb[row] = 1.0f + t - n;
    }
  } else if (row < B_N + N_N) {
    int r = row - B_N;
    const float4 a = *(const float4*)(neg + (size_t)r * D_N + lane * 4);
    float n = a.x * a.x + a.y * a.y + a.z * a.z + a.w * a.w;
    uint2 p;
    p.x = pack2bf(a.x, a.y);
    p.y = pack2bf(a.z, a.w);
    *(uint2*)(neg_bf + (size_t)r * D_N + lane * 4) = p;
    n = wave_reduce_sum(n);
    if (lane == 0) nn2[r] = n;
  } else {
    int r = row - (B_N + N_N);
    const float4 a = *(const float4*)(F + (size_t)r * D_N + lane * 4);
    float n = a.x * a.x + a.y * a.y + a.z * a.z + a.w * a.w;
    n = wave_reduce_sum(n);
    if (lane == 0) fn2[r] = n;
  }
}

// --- main: ju MFMA tiles [0,1024) | jt rows [1024,3072) | ortho [3072,3136) -
__global__ __launch_bounds__(256) void main_kernel(
    const unsigned short* __restrict__ vhat_bf, const unsigned short* __restrict__ neg_bf,
    const float* __restrict__ g, const float* __restrict__ F,
    const float* __restrict__ vhat_f,
    const float* __restrict__ td, const float* __restrict__ vn2,
    const float* __restrict__ cb, const float* __restrict__ nn2,
    const float* __restrict__ fn2, const int* __restrict__ mask,
    float* __restrict__ ju_part, float* __restrict__ jt_row,
    float* __restrict__ or_part) {
  __shared__ __align__(16) unsigned char smem[16384];
  const int bx = blockIdx.x;
  const int tid = threadIdx.x;
  const int lane = tid & 63;
  const int wave = tid >> 6;

  if (bx < 1024) {
    // ================= Ju: bf16 MFMA GEMM, 128x128 tile ====================
    unsigned short* AsU = (unsigned short*)smem;       // 128 rows x 32 k (bf16)
    unsigned short* BsU = AsU + 4096;
    const int b0 = (bx >> 4) * 128;
    const int n0 = (bx & 15) * 128;
    const int wx = wave & 1, wy = wave >> 1;

    // staging: each wave stages 2x1KB for A and 2x1KB for B per k-chunk.
    // LDS slot (r, c_slot) holds global 16B-chunk c_g = c_slot ^ ((r>>1)&3)
    // (XOR swizzle -> conflict-free b128 fragment reads).
    const int c_slot = lane & 3;
    const int rA0 = wave * 32 + (lane >> 2);
    const int rA1 = rA0 + 16;
    const int cg0 = c_slot ^ ((rA0 >> 1) & 3);
    const int cg1 = c_slot ^ ((rA1 >> 1) & 3);
    const unsigned short* gA0 = vhat_bf + (size_t)(b0 + rA0) * D_N + cg0 * 8;
    const unsigned short* gA1 = vhat_bf + (size_t)(b0 + rA1) * D_N + cg1 * 8;
    const unsigned short* gB0 = neg_bf + (size_t)(n0 + rA0) * D_N + cg0 * 8;
    const unsigned short* gB1 = neg_bf + (size_t)(n0 + rA1) * D_N + cg1 * 8;
    unsigned short* lA0 = AsU + wave * 1024 + lane * 8;
    unsigned short* lA1 = lA0 + 512;
    unsigned short* lB0 = BsU + wave * 1024 + lane * 8;
    unsigned short* lB1 = lB0 + 512;

    // fragment LDS offsets (constant over k-loop)
    const int fr = lane & 15;
    const int fc = lane >> 4;  // global k-chunk wanted by this lane
    int aoff[4], boff[4];
    #pragma unroll
    for (int i = 0; i < 4; ++i) {
      int ra = wy * 64 + i * 16 + fr;
      aoff[i] = ra * 32 + (fc ^ ((ra >> 1) & 3)) * 8;
      int rb = wx * 64 + i * 16 + fr;
      boff[i] = rb * 32 + (fc ^ ((rb >> 1) & 3)) * 8;
    }

    floatx4 acc[4][4];
    #pragma unroll
    for (int i = 0; i < 4; ++i)
      #pragma unroll
      for (int j = 0; j < 4; ++j)
        acc[i][j] = floatx4{0.0f, 0.0f, 0.0f, 0.0f};

    for (int k0 = 0; k0 < D_N; k0 += 32) {
      __syncthreads();
      gload16(gA0 + k0, lA0);
      gload16(gA1 + k0, lA1);
      gload16(gB0 + k0, lB0);
      gload16(gB1 + k0, lB1);
      __syncthreads();
      short8 af[4], bf[4];
      #pragma unroll
      for (int i = 0; i < 4; ++i) af[i] = *(const short8*)(AsU + aoff[i]);
      #pragma unroll
      for (int j = 0; j < 4; ++j) bf[j] = *(const short8*)(BsU + boff[j]);
      #pragma unroll
      for (int i = 0; i < 4; ++i)
        #pragma unroll
        for (int j = 0; j < 4; ++j)
          acc[i][j] = __builtin_amdgcn_mfma_f32_16x16x32_bf16(af[i], bf[j], acc[i][j], 0, 0, 0);
    }

    // epilogue: C/D layout col=lane&15 (n), row=(lane>>4)*4+reg (b)
    float nns[4];
    #pragma unroll
    for (int j = 0; j < 4; ++j)
      nns[j] = nn2[n0 + wx * 64 + j * 16 + (lane & 15)];
    float lsum = 0.0f;
    #pragma unroll
    for (int i = 0; i < 4; ++i) {
      #pragma unroll
      for (int r = 0; r < 4; ++r) {
        int b = b0 + wy * 64 + i * 16 + (lane >> 4) * 4 + r;
        float cbb = cb[b];
        float mf = (mask[b] != 0) ? 1.0f : 0.0f;
        float rs = 0.0f;
        #pragma unroll
        for (int j = 0; j < 4; ++j) {
          float val = cbb + 2.0f * acc[i][j][r] - nns[j];
          rs += fmaxf(val, 0.0f);
        }
        lsum += mf * rs;
      }
    }
    lsum = wave_reduce_sum(lsum);
    if (lane == 0) ju_part[bx * 4 + wave] = lsum;

  } else if (bx < 3072) {
    // ================= Jt: bottom-8-of-512 + 8 dots, one wave per row ======
    int b = ((bx - 1024) << 2) + wave;
    const float* grow = g + (size_t)b * K_N;
    float gv[8];
    {
      float4 g0 = *(const float4*)(grow + lane * 8);
      float4 g1 = *(const float4*)(grow + lane * 8 + 4);
      gv[0] = g0.x; gv[1] = g0.y; gv[2] = g0.z; gv[3] = g0.w;
      gv[4] = g1.x; gv[5] = g1.y; gv[6] = g1.z; gv[7] = g1.w;
    }
    unsigned used = 0;
    float sel_val[T_N];
    int sel_idx[T_N];
    for (int t = 0; t < T_N; ++t) {
      float lv = 3.0e38f;
      int lj = 0;
      #pragma unroll
      for (int j = 0; j < 8; ++j) {
        bool ok = (((used >> j) & 1u) == 0u) && (gv[j] < lv);
        lv = ok ? gv[j] : lv;
        lj = ok ? j : lj;
      }
      float rv = lv;
      int ri = lane * 8 + lj;
      #pragma unroll
      for (int off = 32; off > 0; off >>= 1) {
        float ov = __shfl_down(rv, off, 64);
        int oi = __shfl_down(ri, off, 64);
        if (ov < rv) { rv = ov; ri = oi; }
      }
      rv = __shfl(rv, 0, 64);
      ri = __shfl(ri, 0, 64);
      if ((ri >> 3) == lane) used |= 1u << (ri & 7);
      sel_val[t] = rv;
      sel_idx[t] = ri;
    }
    float gsum = 1e-10f;
    #pragma unroll
    for (int t = 0; t < T_N; ++t) gsum += sel_val[t];
    float4 vh = *(const float4*)(vhat_f + (size_t)b * D_N + lane * 4);
    float tdb = td[b], vnb = vn2[b];
    float jtb = 0.0f;
    #pragma unroll
    for (int t = 0; t < T_N; ++t) {
      const float* Fr = F + (size_t)sel_idx[t] * D_N;
      float4 f4 = *(const float4*)(Fr + lane * 4);
      float p = vh.x * f4.x + vh.y * f4.y + vh.z * f4.z + vh.w * f4.w;
      p = wave_reduce_sum(p);
      p = __shfl(p, 0, 64);
      float dneg = vnb - 2.0f * p + fn2[sel_idx[t]];
      float gt = sel_val[t] / gsum;
      float mt = (1.0f - gt) * (1.0f - gt);
      float cur = mt + tdb - dneg;
      jtb += cur > 0.0f ? cur : 0.0f;
    }
    if (lane == 0) jt_row[b] = jtb * ((mask[b] != 0) ? 1.0f : 0.0f);

  } else {
    // ================= ortho: ||F F^T - I||_F^2, 64x64 f32 tiles ===========
    float (*As)[68] = (float(*)[68])smem;
    float (*Bs)[68] = (float(*)[68])(smem + 16 * 68 * 4);
    int o = bx - 3072;
    int i0 = (o >> 3) << 6, j0 = (o & 7) << 6;
    int tx = tid & 15, ty = tid >> 4;
    int lrow = tid >> 2;
    int lc = (tid & 3) << 2;
    float acc[4][4] = {};
    const float* aptr = F + (size_t)(i0 + lrow) * D_N + lc;
    const float* bptr = F + (size_t)(j0 + lrow) * D_N + lc;
    for (int d0 = 0; d0 < D_N; d0 += 16) {
      float4 av = *(const float4*)(aptr + d0);
      float4 bv = *(const float4*)(bptr + d0);
      __syncthreads();
      As[lc + 0][lrow] = av.x; As[lc + 1][lrow] = av.y;
      As[lc + 2][lrow] = av.z; As[lc + 3][lrow] = av.w;
      Bs[lc + 0][lrow] = bv.x; Bs[lc + 1][lrow] = bv.y;
      Bs[lc + 2][lrow] = bv.z; Bs[lc + 3][lrow] = bv.w;
      __syncthreads();
      #pragma unroll
      for (int dd = 0; dd < 16; ++dd) {
        float4 a4 = *(const float4*)&As[dd][ty << 2];
        float4 b4 = *(const float4*)&Bs[dd][tx << 2];
        float ar[4] = {a4.x, a4.y, a4.z, a4.w};
        float br[4] = {b4.x, b4.y, b4.z, b4.w};
        #pragma unroll
        for (int i = 0; i < 4; ++i)
          #pragma unroll
          for (int j = 0; j < 4; ++j)
            acc[i][j] = fmaf(ar[i], br[j], acc[i][j]);
      }
    }
    float bsum = 0.0f;
    #pragma unroll
    for (int i = 0; i < 4; ++i) {
      int gi = i0 + (ty << 2) + i;
      #pragma unroll
      for (int j = 0; j < 4; ++j) {
        int gj = j0 + (tx << 2) + j;
        float s = acc[i][j] - (gi == gj ? 1.0f : 0.0f);
        bsum += s * s;
      }
    }
    bsum = wave_reduce_sum(bsum);
    if (lane == 0) or_part[o * 4 + wave] = bsum;
  }
}

// --- finalize: sum all partials, compute output -----------------------------
__global__ __launch_bounds__(256) void finalize_kernel(
    const float* __restrict__ jt_row, const float* __restrict__ ju_part,
    const float* __restrict__ or_part, const int* __restrict__ mask,
    float* __restrict__ out) {
  int tid = threadIdx.x;
  float sjt = 0.0f, sju = 0.0f, sor = 0.0f, sm = 0.0f;
  for (int i = tid; i < B_N; i += 256) {
    sjt += jt_row[i];
    sm += (mask[i] != 0) ? 1.0f : 0.0f;
  }
  for (int i = tid; i < 4096; i += 256) sju += ju_part[i];
  sor = or_part[tid];
  sjt = wave_reduce_sum(sjt);
  sju = wave_reduce_sum(sju);
  sor = wave_reduce_sum(sor);
  sm  = wave_reduce_sum(sm);
  __shared__ float red[4][4];
  int lane = tid & 63, w = tid >> 6;
  if (lane == 0) {
    red[w][0] = sjt; red[w][1] = sju; red[w][2] = sor; red[w][3] = sm;
  }
  __syncthreads();
  if (tid == 0) {
    float jt = red[0][0] + red[1][0] + red[2][0] + red[3][0];
    float ju = red[0][1] + red[1][1] + red[2][1] + red[3][1];
    float oo = red[0][2] + red[1][2] + red[2][2] + red[3][2];
    float ms = red[0][3] + red[1][3] + red[2][3] + red[3][3];
    float Ju = (ms == 0.0f) ? 0.0f : ju / ((float)N_N * ms);
    float Jt = (ms == 0.0f) ? 0.0f : jt / ms;
    out[0] = Ju + Jt + 1.0e-3f * oo;
  }
}

extern "C" void kernel_launch(void* const* d_in, const int* in_sizes, int n_in,
                              void* d_out, int out_size, void* d_ws, size_t ws_size,
                              hipStream_t stream) {
  (void)in_sizes; (void)n_in; (void)out_size; (void)ws_size;
  const float* v    = (const float*)d_in[0];
  const float* vhat = (const float*)d_in[1];
  const float* g    = (const float*)d_in[2];
  const float* F    = (const float*)d_in[3];
  const float* neg  = (const float*)d_in[4];
  const int*   mask = (const int*)d_in[5];

  float* ws = (float*)d_ws;
  float* td      = ws;
  float* vn2     = ws + 8192;
  float* cb      = ws + 16384;
  float* nn2     = ws + 24576;
  float* fn2     = ws + 26624;
  float* jt_row  = ws + 27136;
  float* ju_part = ws + 35328;
  float* or_part = ws + 39424;
  unsigned short* vhat_bf = (unsigned short*)(ws + 39680);
  unsigned short* neg_bf  = vhat_bf + (size_t)B_N * D_N;

  prep_kernel<<<(B_N + N_N + K_N) / 4, 256, 0, stream>>>(
      v, vhat, neg, F, vhat_bf, neg_bf, td, vn2, cb, nn2, fn2);
  main_kernel<<<1024 + 2048 + 64, 256, 0, stream>>>(
      vhat_bf, neg_bf, g, F, vhat, td, vn2, cb, nn2, fn2, mask,
      ju_part, jt_row, or_part);
  finalize_kernel<<<1, 256, 0, stream>>>(jt_row, ju_part, or_part, mask, (float*)d_out);
}

// Round 4
// 127.817 us; speedup vs baseline: 2.6114x; 1.1252x over previous
//
#include <hip/hip_runtime.h>

// Problem constants (fixed by reference setup_inputs)
#define B_N 8192
#define D_N 256
#define N_N 2048
#define K_N 512
#define T_N 8

using short8  = __attribute__((ext_vector_type(8))) short;
using floatx4 = __attribute__((ext_vector_type(4))) float;

// ---------------------------------------------------------------------------
// Workspace layout (float units):
//  td      = ws + 0        [8192]
//  vn2     = ws + 8192     [8192]
//  cb      = ws + 16384    [8192]
//  nn2     = ws + 24576    [2048]
//  fn2     = ws + 26624    [512]
//  jt_row  = ws + 27136    [8192]
//  ju_part = ws + 35328    [4096]
//  or_part = ws + 39424    [64]
//  vhat_bf = (ushort*)(ws + 39680)   [8192*256]   (16B aligned)
//  neg_bf  = vhat_bf + 8192*256      [2048*256]
//  F_bf    = neg_bf + 2048*256       [512*256]
// ---------------------------------------------------------------------------

__device__ __forceinline__ float wave_reduce_sum(float x) {
  #pragma unroll
  for (int off = 32; off > 0; off >>= 1) x += __shfl_down(x, off, 64);
  return x;
}

__device__ __forceinline__ unsigned int f2bf(float x) {
  unsigned u = __float_as_uint(x);
  return (u + 0x7fffu + ((u >> 16) & 1u)) >> 16;
}

__device__ __forceinline__ unsigned int pack2bf(float x, float y) {
  return f2bf(x) | (f2bf(y) << 16);
}

// async global->LDS, 16 bytes per lane; LDS dest is wave-uniform base + lane*16
__device__ __forceinline__ void gload16(const unsigned short* g, unsigned short* l) {
  __builtin_amdgcn_global_load_lds(
      (const __attribute__((address_space(1))) unsigned int*)g,
      (__attribute__((address_space(3))) unsigned int*)l, 16, 0, 0);
}

// --- prep: all row stats + f32->bf16 conversion of vhat/neg/F ---------------
// one row per wave; rows [0,B)=vhat(+v), [B,B+N)=neg, [B+N,B+N+K)=F
__global__ __launch_bounds__(256) void prep_kernel(
    const float* __restrict__ v, const float* __restrict__ vhat,
    const float* __restrict__ neg, const float* __restrict__ F,
    unsigned short* __restrict__ vhat_bf, unsigned short* __restrict__ neg_bf,
    unsigned short* __restrict__ F_bf,
    float* __restrict__ td, float* __restrict__ vn2, float* __restrict__ cb,
    float* __restrict__ nn2, float* __restrict__ fn2) {
  int lane = threadIdx.x & 63;
  int row = (blockIdx.x << 2) + (threadIdx.x >> 6);
  if (row < B_N) {
    const float4 a = *(const float4*)(vhat + (size_t)row * D_N + lane * 4);
    const float4 b = *(const float4*)(v + (size_t)row * D_N + lane * 4);
    float dx = a.x - b.x, dy = a.y - b.y, dz = a.z - b.z, dw = a.w - b.w;
    float t = dx * dx + dy * dy + dz * dz + dw * dw;
    float n = a.x * a.x + a.y * a.y + a.z * a.z + a.w * a.w;
    uint2 p;
    p.x = pack2bf(a.x, a.y);
    p.y = pack2bf(a.z, a.w);
    *(uint2*)(vhat_bf + (size_t)row * D_N + lane * 4) = p;
    t = wave_reduce_sum(t);
    n = wave_reduce_sum(n);
    if (lane == 0) {
      td[row] = t;
      vn2[row] = n;
      cb[row] = 1.0f + t - n;
    }
  } else if (row < B_N + N_N) {
    int r = row - B_N;
    const float4 a = *(const float4*)(neg + (size_t)r * D_N + lane * 4);
    float n = a.x * a.x + a.y * a.y + a.z * a.z + a.w * a.w;
    uint2 p;
    p.x = pack2bf(a.x, a.y);
    p.y = pack2bf(a.z, a.w);
    *(uint2*)(neg_bf + (size_t)r * D_N + lane * 4) = p;
    n = wave_reduce_sum(n);
    if (lane == 0) nn2[r] = n;
  } else {
    int r = row - (B_N + N_N);
    const float4 a = *(const float4*)(F + (size_t)r * D_N + lane * 4);
    float n = a.x * a.x + a.y * a.y + a.z * a.z + a.w * a.w;
    uint2 p;
    p.x = pack2bf(a.x, a.y);
    p.y = pack2bf(a.z, a.w);
    *(uint2*)(F_bf + (size_t)r * D_N + lane * 4) = p;
    n = wave_reduce_sum(n);
    if (lane == 0) fn2[r] = n;
  }
}

// --- main: ju tiles [0,1024) | ortho tiles [1024,1040) | jt rows [1040,3088)
__global__ __launch_bounds__(256) void main_kernel(
    const unsigned short* __restrict__ vhat_bf, const unsigned short* __restrict__ neg_bf,
    const unsigned short* __restrict__ F_bf,
    const float* __restrict__ g, const float* __restrict__ F,
    const float* __restrict__ vhat_f,
    const float* __restrict__ td, const float* __restrict__ vn2,
    const float* __restrict__ cb, const float* __restrict__ nn2,
    const float* __restrict__ fn2, const int* __restrict__ mask,
    float* __restrict__ ju_part, float* __restrict__ jt_row,
    float* __restrict__ or_part) {
  __shared__ __align__(16) unsigned char smem[16384];
  const int bx = blockIdx.x;
  const int tid = threadIdx.x;
  const int lane = tid & 63;
  const int wave = tid >> 6;

  if (bx < 1040) {
    // ============ bf16 MFMA GEMM, 128x128 tile (ju and ortho) ==============
    const bool is_ju = bx < 1024;
    unsigned short* AsU = (unsigned short*)smem;       // 128 rows x 32 k (bf16)
    unsigned short* BsU = AsU + 4096;
    int r0, c0;  // tile origin: rows of A, rows of B
    const unsigned short *Abase, *Bbase;
    if (is_ju) {
      r0 = (bx >> 4) * 128;
      c0 = (bx & 15) * 128;
      Abase = vhat_bf;
      Bbase = neg_bf;
    } else {
      int o = bx - 1024;
      r0 = (o >> 2) * 128;
      c0 = (o & 3) * 128;
      Abase = F_bf;
      Bbase = F_bf;
    }
    const int wx = wave & 1, wy = wave >> 1;

    // staging: LDS slot (r, c_slot) holds global 16B-chunk c_g = c_slot ^ ((r>>1)&3)
    const int c_slot = lane & 3;
    const int rA0 = wave * 32 + (lane >> 2);
    const int rA1 = rA0 + 16;
    const int cg0 = c_slot ^ ((rA0 >> 1) & 3);
    const int cg1 = c_slot ^ ((rA1 >> 1) & 3);
    const unsigned short* gA0 = Abase + (size_t)(r0 + rA0) * D_N + cg0 * 8;
    const unsigned short* gA1 = Abase + (size_t)(r0 + rA1) * D_N + cg1 * 8;
    const unsigned short* gB0 = Bbase + (size_t)(c0 + rA0) * D_N + cg0 * 8;
    const unsigned short* gB1 = Bbase + (size_t)(c0 + rA1) * D_N + cg1 * 8;
    unsigned short* lA0 = AsU + wave * 1024 + lane * 8;
    unsigned short* lA1 = lA0 + 512;
    unsigned short* lB0 = BsU + wave * 1024 + lane * 8;
    unsigned short* lB1 = lB0 + 512;

    // fragment LDS offsets (constant over k-loop)
    const int fr = lane & 15;
    const int fc = lane >> 4;  // global k-chunk wanted by this lane
    int aoff[4], boff[4];
    #pragma unroll
    for (int i = 0; i < 4; ++i) {
      int ra = wy * 64 + i * 16 + fr;
      aoff[i] = ra * 32 + (fc ^ ((ra >> 1) & 3)) * 8;
      int rb = wx * 64 + i * 16 + fr;
      boff[i] = rb * 32 + (fc ^ ((rb >> 1) & 3)) * 8;
    }

    floatx4 acc[4][4];
    #pragma unroll
    for (int i = 0; i < 4; ++i)
      #pragma unroll
      for (int j = 0; j < 4; ++j)
        acc[i][j] = floatx4{0.0f, 0.0f, 0.0f, 0.0f};

    for (int k0 = 0; k0 < D_N; k0 += 32) {
      __syncthreads();
      gload16(gA0 + k0, lA0);
      gload16(gA1 + k0, lA1);
      gload16(gB0 + k0, lB0);
      gload16(gB1 + k0, lB1);
      __syncthreads();
      short8 af[4], bf[4];
      #pragma unroll
      for (int i = 0; i < 4; ++i) af[i] = *(const short8*)(AsU + aoff[i]);
      #pragma unroll
      for (int j = 0; j < 4; ++j) bf[j] = *(const short8*)(BsU + boff[j]);
      #pragma unroll
      for (int i = 0; i < 4; ++i)
        #pragma unroll
        for (int j = 0; j < 4; ++j)
          acc[i][j] = __builtin_amdgcn_mfma_f32_16x16x32_bf16(af[i], bf[j], acc[i][j], 0, 0, 0);
    }

    // epilogue: C/D layout col=lane&15 (n/j), row=(lane>>4)*4+reg (b/i)
    if (is_ju) {
      float nns[4];
      #pragma unroll
      for (int j = 0; j < 4; ++j)
        nns[j] = nn2[c0 + wx * 64 + j * 16 + (lane & 15)];
      float lsum = 0.0f;
      #pragma unroll
      for (int i = 0; i < 4; ++i) {
        #pragma unroll
        for (int r = 0; r < 4; ++r) {
          int b = r0 + wy * 64 + i * 16 + (lane >> 4) * 4 + r;
          float cbb = cb[b];
          float mf = (mask[b] != 0) ? 1.0f : 0.0f;
          float rs = 0.0f;
          #pragma unroll
          for (int j = 0; j < 4; ++j) {
            float val = cbb + 2.0f * acc[i][j][r] - nns[j];
            rs += fmaxf(val, 0.0f);
          }
          lsum += mf * rs;
        }
      }
      lsum = wave_reduce_sum(lsum);
      if (lane == 0) ju_part[bx * 4 + wave] = lsum;
    } else {
      // ortho: sum (gram - I)^2; diagonal computed exactly from f32 fn2
      float lsum = 0.0f;
      #pragma unroll
      for (int i = 0; i < 4; ++i) {
        #pragma unroll
        for (int r = 0; r < 4; ++r) {
          int gi = r0 + wy * 64 + i * 16 + (lane >> 4) * 4 + r;
          #pragma unroll
          for (int j = 0; j < 4; ++j) {
            int gj = c0 + wx * 64 + j * 16 + (lane & 15);
            float s = (gi == gj) ? (fn2[gi] - 1.0f) : acc[i][j][r];
            lsum += s * s;
          }
        }
      }
      lsum = wave_reduce_sum(lsum);
      if (lane == 0) or_part[(bx - 1024) * 4 + wave] = lsum;
    }

  } else {
    // ================= Jt: bottom-8-of-512 + 8 dots, one wave per row ======
    int b = ((bx - 1040) << 2) + wave;
    const float* grow = g + (size_t)b * K_N;
    float gv[8];
    {
      float4 g0 = *(const float4*)(grow + lane * 8);
      float4 g1 = *(const float4*)(grow + lane * 8 + 4);
      gv[0] = g0.x; gv[1] = g0.y; gv[2] = g0.z; gv[3] = g0.w;
      gv[4] = g1.x; gv[5] = g1.y; gv[6] = g1.z; gv[7] = g1.w;
    }
    unsigned used = 0;
    float sel_val[T_N];
    int sel_idx[T_N];
    for (int t = 0; t < T_N; ++t) {
      float lv = 3.0e38f;
      int lj = 0;
      #pragma unroll
      for (int j = 0; j < 8; ++j) {
        bool ok = (((used >> j) & 1u) == 0u) && (gv[j] < lv);
        lv = ok ? gv[j] : lv;
        lj = ok ? j : lj;
      }
      float rv = lv;
      int ri = lane * 8 + lj;
      #pragma unroll
      for (int off = 32; off > 0; off >>= 1) {
        float ov = __shfl_down(rv, off, 64);
        int oi = __shfl_down(ri, off, 64);
        if (ov < rv) { rv = ov; ri = oi; }
      }
      rv = __shfl(rv, 0, 64);
      ri = __shfl(ri, 0, 64);
      if ((ri >> 3) == lane) used |= 1u << (ri & 7);
      sel_val[t] = rv;
      sel_idx[t] = ri;
    }
    float gsum = 1e-10f;
    #pragma unroll
    for (int t = 0; t < T_N; ++t) gsum += sel_val[t];
    float4 vh = *(const float4*)(vhat_f + (size_t)b * D_N + lane * 4);
    float tdb = td[b], vnb = vn2[b];
    float jtb = 0.0f;
    #pragma unroll
    for (int t = 0; t < T_N; ++t) {
      const float* Fr = F + (size_t)sel_idx[t] * D_N;
      float4 f4 = *(const float4*)(Fr + lane * 4);
      float p = vh.x * f4.x + vh.y * f4.y + vh.z * f4.z + vh.w * f4.w;
      p = wave_reduce_sum(p);
      p = __shfl(p, 0, 64);
      float dneg = vnb - 2.0f * p + fn2[sel_idx[t]];
      float gt = sel_val[t] / gsum;
      float mt = (1.0f - gt) * (1.0f - gt);
      float cur = mt + tdb - dneg;
      jtb += cur > 0.0f ? cur : 0.0f;
    }
    if (lane == 0) jt_row[b] = jtb * ((mask[b] != 0) ? 1.0f : 0.0f);
  }
}

// --- finalize: sum all partials, compute output -----------------------------
__global__ __launch_bounds__(256) void finalize_kernel(
    const float* __restrict__ jt_row, const float* __restrict__ ju_part,
    const float* __restrict__ or_part, const int* __restrict__ mask,
    float* __restrict__ out) {
  int tid = threadIdx.x;
  float sjt = 0.0f, sju = 0.0f, sor = 0.0f, sm = 0.0f;
  for (int i = tid; i < B_N; i += 256) {
    sjt += jt_row[i];
    sm += (mask[i] != 0) ? 1.0f : 0.0f;
  }
  for (int i = tid; i < 4096; i += 256) sju += ju_part[i];
  if (tid < 64) sor = or_part[tid];
  sjt = wave_reduce_sum(sjt);
  sju = wave_reduce_sum(sju);
  sor = wave_reduce_sum(sor);
  sm  = wave_reduce_sum(sm);
  __shared__ float red[4][4];
  int lane = tid & 63, w = tid >> 6;
  if (lane == 0) {
    red[w][0] = sjt; red[w][1] = sju; red[w][2] = sor; red[w][3] = sm;
  }
  __syncthreads();
  if (tid == 0) {
    float jt = red[0][0] + red[1][0] + red[2][0] + red[3][0];
    float ju = red[0][1] + red[1][1] + red[2][1] + red[3][1];
    float oo = red[0][2] + red[1][2] + red[2][2] + red[3][2];
    float ms = red[0][3] + red[1][3] + red[2][3] + red[3][3];
    float Ju = (ms == 0.0f) ? 0.0f : ju / ((float)N_N * ms);
    float Jt = (ms == 0.0f) ? 0.0f : jt / ms;
    out[0] = Ju + Jt + 1.0e-3f * oo;
  }
}

extern "C" void kernel_launch(void* const* d_in, const int* in_sizes, int n_in,
                              void* d_out, int out_size, void* d_ws, size_t ws_size,
                              hipStream_t stream) {
  (void)in_sizes; (void)n_in; (void)out_size; (void)ws_size;
  const float* v    = (const float*)d_in[0];
  const float* vhat = (const float*)d_in[1];
  const float* g    = (const float*)d_in[2];
  const float* F    = (const float*)d_in[3];
  const float* neg  = (const float*)d_in[4];
  const int*   mask = (const int*)d_in[5];

  float* ws = (float*)d_ws;
  float* td      = ws;
  float* vn2     = ws + 8192;
  float* cb      = ws + 16384;
  float* nn2     = ws + 24576;
  float* fn2     = ws + 26624;
  float* jt_row  = ws + 27136;
  float* ju_part = ws + 35328;
  float* or_part = ws + 39424;
  unsigned short* vhat_bf = (unsigned short*)(ws + 39680);
  unsigned short* neg_bf  = vhat_bf + (size_t)B_N * D_N;
  unsigned short* F_bf    = neg_bf + (size_t)N_N * D_N;

  prep_kernel<<<(B_N + N_N + K_N) / 4, 256, 0, stream>>>(
      v, vhat, neg, F, vhat_bf, neg_bf, F_bf, td, vn2, cb, nn2, fn2);
  main_kernel<<<1024 + 16 + 2048, 256, 0, stream>>>(
      vhat_bf, neg_bf, F_bf, g, F, vhat, td, vn2, cb, nn2, fn2, mask,
      ju_part, jt_row, or_part);
  finalize_kernel<<<1, 256, 0, stream>>>(jt_row, ju_part, or_part, mask, (float*)d_out);
}

// Round 5
// 126.314 us; speedup vs baseline: 2.6424x; 1.0119x over previous
//
#include <hip/hip_runtime.h>

// Problem constants (fixed by reference setup_inputs)
#define B_N 8192
#define D_N 256
#define N_N 2048
#define K_N 512
#define T_N 8

using short8  = __attribute__((ext_vector_type(8))) short;
using floatx4 = __attribute__((ext_vector_type(4))) float;

// ---------------------------------------------------------------------------
// Workspace layout (float units):
//  W       = ws + 0         [8192*512]          (vhat . F^T, f32)
//  td      = ws + 4194304   [8192]
//  vn2     = ws + 4202496   [8192]
//  cb      = ws + 4210688   [8192]
//  nn2     = ws + 4218880   [2048]
//  fn2     = ws + 4220928   [512]
//  ju_part = ws + 4221440   [4096]
//  or_part = ws + 4225536   [64]
//  jt_part = ws + 4225600   [32]
//  selc    = ws + 4225632   [8192*8]  (m_t + td - vn2 per selected t)
//  seli    = (int*) ws + 4291168 [8192*8]
//  vhat_bf = (ushort*)(ws + 4356704)  [8192*256]
//  neg_bf  = vhat_bf + 8192*256       [2048*256]
//  F_bf    = neg_bf + 2048*256        [512*256]
// ---------------------------------------------------------------------------

__device__ __forceinline__ float wave_reduce_sum(float x) {
  #pragma unroll
  for (int off = 32; off > 0; off >>= 1) x += __shfl_down(x, off, 64);
  return x;
}

__device__ __forceinline__ unsigned int f2bf(float x) {
  unsigned u = __float_as_uint(x);
  return (u + 0x7fffu + ((u >> 16) & 1u)) >> 16;
}

__device__ __forceinline__ unsigned int pack2bf(float x, float y) {
  return f2bf(x) | (f2bf(y) << 16);
}

// async global->LDS, 16 bytes per lane; LDS dest is wave-uniform base + lane*16
__device__ __forceinline__ void gload16(const unsigned short* g, unsigned short* l) {
  __builtin_amdgcn_global_load_lds(
      (const __attribute__((address_space(1))) unsigned int*)g,
      (__attribute__((address_space(3))) unsigned int*)l, 16, 0, 0);
}

// compare-swap keeping (val,idx) pairs together
#define CSWAP(a, b)                                              \
  {                                                              \
    bool sw_ = sv[a] > sv[b];                                    \
    float tv_ = sw_ ? sv[a] : sv[b];                             \
    sv[a] = sw_ ? sv[b] : sv[a];                                 \
    sv[b] = tv_;                                                 \
    int ti_ = sw_ ? si[a] : si[b];                               \
    si[a] = sw_ ? si[b] : si[a];                                 \
    si[b] = ti_;                                                 \
  }

// --- prep: stats + bf16 conversion + bottom-8 selection on g ----------------
// one row per wave; rows [0,B)=vhat(+v,+g-selection), [B,B+N)=neg, [B+N,..)=F
__global__ __launch_bounds__(256) void prep_kernel(
    const float* __restrict__ v, const float* __restrict__ vhat,
    const float* __restrict__ neg, const float* __restrict__ F,
    const float* __restrict__ g,
    unsigned short* __restrict__ vhat_bf, unsigned short* __restrict__ neg_bf,
    unsigned short* __restrict__ F_bf,
    float* __restrict__ td, float* __restrict__ vn2, float* __restrict__ cb,
    float* __restrict__ nn2, float* __restrict__ fn2,
    float* __restrict__ selc, int* __restrict__ seli) {
  int lane = threadIdx.x & 63;
  int row = (blockIdx.x << 2) + (threadIdx.x >> 6);
  if (row < B_N) {
    const float4 a = *(const float4*)(vhat + (size_t)row * D_N + lane * 4);
    const float4 b = *(const float4*)(v + (size_t)row * D_N + lane * 4);
    float dx = a.x - b.x, dy = a.y - b.y, dz = a.z - b.z, dw = a.w - b.w;
    float t = dx * dx + dy * dy + dz * dz + dw * dw;
    float n = a.x * a.x + a.y * a.y + a.z * a.z + a.w * a.w;
    uint2 p;
    p.x = pack2bf(a.x, a.y);
    p.y = pack2bf(a.z, a.w);
    *(uint2*)(vhat_bf + (size_t)row * D_N + lane * 4) = p;
    t = wave_reduce_sum(t);
    n = wave_reduce_sum(n);
    if (lane == 0) {
      td[row] = t;
      vn2[row] = n;
      cb[row] = 1.0f + t - n;
    }
    // ---- bottom-8-of-512 selection on g[row] ----
    const float* grow = g + (size_t)row * K_N;
    float sv[8];
    int si[8];
    {
      float4 g0 = *(const float4*)(grow + lane * 8);
      float4 g1 = *(const float4*)(grow + lane * 8 + 4);
      sv[0] = g0.x; sv[1] = g0.y; sv[2] = g0.z; sv[3] = g0.w;
      sv[4] = g1.x; sv[5] = g1.y; sv[6] = g1.z; sv[7] = g1.w;
      #pragma unroll
      for (int j = 0; j < 8; ++j) si[j] = lane * 8 + j;
    }
    // Batcher odd-even mergesort, n=8 (19 comparators) -> ascending
    CSWAP(0,1) CSWAP(2,3) CSWAP(4,5) CSWAP(6,7)
    CSWAP(0,2) CSWAP(1,3) CSWAP(4,6) CSWAP(5,7)
    CSWAP(1,2) CSWAP(5,6)
    CSWAP(0,4) CSWAP(1,5) CSWAP(2,6) CSWAP(3,7)
    CSWAP(2,4) CSWAP(3,5)
    CSWAP(1,2) CSWAP(3,4) CSWAP(5,6)
    // 6 butterfly merge rounds: keep lowest 8 of (mine ++ partner)
    #pragma unroll
    for (int rr = 0; rr < 6; ++rr) {
      const int msk = 1 << rr;
      float pv[8];
      int pi[8];
      #pragma unroll
      for (int j = 0; j < 8; ++j) {
        pv[j] = __shfl_xor(sv[j], msk, 64);
        pi[j] = __shfl_xor(si[j], msk, 64);
      }
      float cv[8];
      int ci[8];
      #pragma unroll
      for (int j = 0; j < 8; ++j) {
        bool mine = sv[j] <= pv[7 - j];
        cv[j] = mine ? sv[j] : pv[7 - j];
        ci[j] = mine ? si[j] : pi[7 - j];
      }
      #pragma unroll
      for (int j = 0; j < 8; ++j) { sv[j] = cv[j]; si[j] = ci[j]; }
      // bitonic -> sorted (distances 4,2,1)
      CSWAP(0,4) CSWAP(1,5) CSWAP(2,6) CSWAP(3,7)
      CSWAP(0,2) CSWAP(1,3) CSWAP(4,6) CSWAP(5,7)
      CSWAP(0,1) CSWAP(2,3) CSWAP(4,5) CSWAP(6,7)
    }
    // every lane now holds the global bottom-8 (sorted).
    float gsum = 1e-10f;
    #pragma unroll
    for (int t8 = 0; t8 < T_N; ++t8) gsum += sv[t8];
    if (lane == 0) {
      float base = t - n;  // td - vn2 (valid on lane 0)
      #pragma unroll
      for (int t8 = 0; t8 < T_N; ++t8) {
        float gt = sv[t8] / gsum;
        float mt = (1.0f - gt) * (1.0f - gt);
        selc[(size_t)row * T_N + t8] = mt + base;
        seli[(size_t)row * T_N + t8] = si[t8];
      }
    }
  } else if (row < B_N + N_N) {
    int r = row - B_N;
    const float4 a = *(const float4*)(neg + (size_t)r * D_N + lane * 4);
    float n = a.x * a.x + a.y * a.y + a.z * a.z + a.w * a.w;
    uint2 p;
    p.x = pack2bf(a.x, a.y);
    p.y = pack2bf(a.z, a.w);
    *(uint2*)(neg_bf + (size_t)r * D_N + lane * 4) = p;
    n = wave_reduce_sum(n);
    if (lane == 0) nn2[r] = n;
  } else {
    int r = row - (B_N + N_N);
    const float4 a = *(const float4*)(F + (size_t)r * D_N + lane * 4);
    float n = a.x * a.x + a.y * a.y + a.z * a.z + a.w * a.w;
    uint2 p;
    p.x = pack2bf(a.x, a.y);
    p.y = pack2bf(a.z, a.w);
    *(uint2*)(F_bf + (size_t)r * D_N + lane * 4) = p;
    n = wave_reduce_sum(n);
    if (lane == 0) fn2[r] = n;
  }
}

// --- main: all-MFMA. ju tiles [0,1024) | ortho [1024,1040) | W [1040,1296) --
__global__ __launch_bounds__(256) void main_kernel(
    const unsigned short* __restrict__ vhat_bf, const unsigned short* __restrict__ neg_bf,
    const unsigned short* __restrict__ F_bf,
    const float* __restrict__ cb, const float* __restrict__ nn2,
    const float* __restrict__ fn2, const int* __restrict__ mask,
    float* __restrict__ ju_part, float* __restrict__ or_part,
    float* __restrict__ W) {
  __shared__ __align__(16) unsigned char smem[16384];
  const int bx = blockIdx.x;
  const int tid = threadIdx.x;
  const int lane = tid & 63;
  const int wave = tid >> 6;

  unsigned short* AsU = (unsigned short*)smem;  // 128 rows x 32 k (bf16)
  unsigned short* BsU = AsU + 4096;
  int r0, c0;
  const unsigned short *Abase, *Bbase;
  int seg;  // 0=ju 1=ortho 2=W
  if (bx < 1024) {
    seg = 0;
    r0 = (bx >> 4) * 128;
    c0 = (bx & 15) * 128;
    Abase = vhat_bf;
    Bbase = neg_bf;
  } else if (bx < 1040) {
    seg = 1;
    int o = bx - 1024;
    r0 = (o >> 2) * 128;
    c0 = (o & 3) * 128;
    Abase = F_bf;
    Bbase = F_bf;
  } else {
    seg = 2;
    int o = bx - 1040;
    r0 = (o >> 2) * 128;
    c0 = (o & 3) * 128;
    Abase = vhat_bf;
    Bbase = F_bf;
  }
  const int wx = wave & 1, wy = wave >> 1;

  // staging: LDS slot (r, c_slot) holds global 16B-chunk c_g = c_slot ^ ((r>>1)&3)
  const int c_slot = lane & 3;
  const int rA0 = wave * 32 + (lane >> 2);
  const int rA1 = rA0 + 16;
  const int cg0 = c_slot ^ ((rA0 >> 1) & 3);
  const int cg1 = c_slot ^ ((rA1 >> 1) & 3);
  const unsigned short* gA0 = Abase + (size_t)(r0 + rA0) * D_N + cg0 * 8;
  const unsigned short* gA1 = Abase + (size_t)(r0 + rA1) * D_N + cg1 * 8;
  const unsigned short* gB0 = Bbase + (size_t)(c0 + rA0) * D_N + cg0 * 8;
  const unsigned short* gB1 = Bbase + (size_t)(c0 + rA1) * D_N + cg1 * 8;
  unsigned short* lA0 = AsU + wave * 1024 + lane * 8;
  unsigned short* lA1 = lA0 + 512;
  unsigned short* lB0 = BsU + wave * 1024 + lane * 8;
  unsigned short* lB1 = lB0 + 512;

  // fragment LDS offsets (constant over k-loop)
  const int fr = lane & 15;
  const int fc = lane >> 4;
  int aoff[4], boff[4];
  #pragma unroll
  for (int i = 0; i < 4; ++i) {
    int ra = wy * 64 + i * 16 + fr;
    aoff[i] = ra * 32 + (fc ^ ((ra >> 1) & 3)) * 8;
    int rb = wx * 64 + i * 16 + fr;
    boff[i] = rb * 32 + (fc ^ ((rb >> 1) & 3)) * 8;
  }

  floatx4 acc[4][4];
  #pragma unroll
  for (int i = 0; i < 4; ++i)
    #pragma unroll
    for (int j = 0; j < 4; ++j)
      acc[i][j] = floatx4{0.0f, 0.0f, 0.0f, 0.0f};

  for (int k0 = 0; k0 < D_N; k0 += 32) {
    __syncthreads();
    gload16(gA0 + k0, lA0);
    gload16(gA1 + k0, lA1);
    gload16(gB0 + k0, lB0);
    gload16(gB1 + k0, lB1);
    __syncthreads();
    short8 af[4], bf[4];
    #pragma unroll
    for (int i = 0; i < 4; ++i) af[i] = *(const short8*)(AsU + aoff[i]);
    #pragma unroll
    for (int j = 0; j < 4; ++j) bf[j] = *(const short8*)(BsU + boff[j]);
    #pragma unroll
    for (int i = 0; i < 4; ++i)
      #pragma unroll
      for (int j = 0; j < 4; ++j)
        acc[i][j] = __builtin_amdgcn_mfma_f32_16x16x32_bf16(af[i], bf[j], acc[i][j], 0, 0, 0);
  }

  // epilogue: C/D layout col=lane&15 (j), row=(lane>>4)*4+reg (i)
  if (seg == 0) {
    float nns[4];
    #pragma unroll
    for (int j = 0; j < 4; ++j)
      nns[j] = nn2[c0 + wx * 64 + j * 16 + (lane & 15)];
    float lsum = 0.0f;
    #pragma unroll
    for (int i = 0; i < 4; ++i) {
      #pragma unroll
      for (int r = 0; r < 4; ++r) {
        int b = r0 + wy * 64 + i * 16 + (lane >> 4) * 4 + r;
        float cbb = cb[b];
        float mf = (mask[b] != 0) ? 1.0f : 0.0f;
        float rs = 0.0f;
        #pragma unroll
        for (int j = 0; j < 4; ++j) {
          float val = cbb + 2.0f * acc[i][j][r] - nns[j];
          rs += fmaxf(val, 0.0f);
        }
        lsum += mf * rs;
      }
    }
    lsum = wave_reduce_sum(lsum);
    if (lane == 0) ju_part[bx * 4 + wave] = lsum;
  } else if (seg == 1) {
    // ortho: sum (gram - I)^2; diagonal computed exactly from f32 fn2
    float lsum = 0.0f;
    #pragma unroll
    for (int i = 0; i < 4; ++i) {
      #pragma unroll
      for (int r = 0; r < 4; ++r) {
        int gi = r0 + wy * 64 + i * 16 + (lane >> 4) * 4 + r;
        #pragma unroll
        for (int j = 0; j < 4; ++j) {
          int gj = c0 + wx * 64 + j * 16 + (lane & 15);
          float s = (gi == gj) ? (fn2[gi] - 1.0f) : acc[i][j][r];
          lsum += s * s;
        }
      }
    }
    lsum = wave_reduce_sum(lsum);
    if (lane == 0) or_part[(bx - 1024) * 4 + wave] = lsum;
  } else {
    // W: store dot products vhat_b . F_k
    #pragma unroll
    for (int i = 0; i < 4; ++i) {
      #pragma unroll
      for (int r = 0; r < 4; ++r) {
        int row = r0 + wy * 64 + i * 16 + (lane >> 4) * 4 + r;
        #pragma unroll
        for (int j = 0; j < 4; ++j) {
          int col = c0 + wx * 64 + j * 16 + (lane & 15);
          W[(size_t)row * K_N + col] = acc[i][j][r];
        }
      }
    }
  }
}

// --- jt gather: one thread per row, 8 gathers from W + clamp ----------------
__global__ __launch_bounds__(256) void jt_gather_kernel(
    const int* __restrict__ seli, const float* __restrict__ selc,
    const float* __restrict__ W, const float* __restrict__ fn2,
    const int* __restrict__ mask, float* __restrict__ jt_part) {
  int b = blockIdx.x * 256 + threadIdx.x;
  int4 i0 = *(const int4*)(seli + (size_t)b * 8);
  int4 i1 = *(const int4*)(seli + (size_t)b * 8 + 4);
  float4 c0 = *(const float4*)(selc + (size_t)b * 8);
  float4 c1 = *(const float4*)(selc + (size_t)b * 8 + 4);
  const float* wrow = W + (size_t)b * K_N;
  float s = 0.0f;
  s += fmaxf(c0.x + 2.0f * wrow[i0.x] - fn2[i0.x], 0.0f);
  s += fmaxf(c0.y + 2.0f * wrow[i0.y] - fn2[i0.y], 0.0f);
  s += fmaxf(c0.z + 2.0f * wrow[i0.z] - fn2[i0.z], 0.0f);
  s += fmaxf(c0.w + 2.0f * wrow[i0.w] - fn2[i0.w], 0.0f);
  s += fmaxf(c1.x + 2.0f * wrow[i1.x] - fn2[i1.x], 0.0f);
  s += fmaxf(c1.y + 2.0f * wrow[i1.y] - fn2[i1.y], 0.0f);
  s += fmaxf(c1.z + 2.0f * wrow[i1.z] - fn2[i1.z], 0.0f);
  s += fmaxf(c1.w + 2.0f * wrow[i1.w] - fn2[i1.w], 0.0f);
  s *= (mask[b] != 0) ? 1.0f : 0.0f;
  s = wave_reduce_sum(s);
  __shared__ float red[4];
  if ((threadIdx.x & 63) == 0) red[threadIdx.x >> 6] = s;
  __syncthreads();
  if (threadIdx.x == 0)
    jt_part[blockIdx.x] = red[0] + red[1] + red[2] + red[3];
}

// --- finalize ---------------------------------------------------------------
__global__ __launch_bounds__(256) void finalize_kernel(
    const float* __restrict__ jt_part, const float* __restrict__ ju_part,
    const float* __restrict__ or_part, const int* __restrict__ mask,
    float* __restrict__ out) {
  int tid = threadIdx.x;
  float sjt = 0.0f, sju = 0.0f, sor = 0.0f, sm = 0.0f;
  for (int i = tid; i < B_N; i += 256) sm += (mask[i] != 0) ? 1.0f : 0.0f;
  for (int i = tid; i < 4096; i += 256) sju += ju_part[i];
  if (tid < 64) sor = or_part[tid];
  if (tid < 32) sjt = jt_part[tid];
  sjt = wave_reduce_sum(sjt);
  sju = wave_reduce_sum(sju);
  sor = wave_reduce_sum(sor);
  sm  = wave_reduce_sum(sm);
  __shared__ float red[4][4];
  int lane = tid & 63, w = tid >> 6;
  if (lane == 0) {
    red[w][0] = sjt; red[w][1] = sju; red[w][2] = sor; red[w][3] = sm;
  }
  __syncthreads();
  if (tid == 0) {
    float jt = red[0][0] + red[1][0] + red[2][0] + red[3][0];
    float ju = red[0][1] + red[1][1] + red[2][1] + red[3][1];
    float oo = red[0][2] + red[1][2] + red[2][2] + red[3][2];
    float ms = red[0][3] + red[1][3] + red[2][3] + red[3][3];
    float Ju = (ms == 0.0f) ? 0.0f : ju / ((float)N_N * ms);
    float Jt = (ms == 0.0f) ? 0.0f : jt / ms;
    out[0] = Ju + Jt + 1.0e-3f * oo;
  }
}

extern "C" void kernel_launch(void* const* d_in, const int* in_sizes, int n_in,
                              void* d_out, int out_size, void* d_ws, size_t ws_size,
                              hipStream_t stream) {
  (void)in_sizes; (void)n_in; (void)out_size; (void)ws_size;
  const float* v    = (const float*)d_in[0];
  const float* vhat = (const float*)d_in[1];
  const float* g    = (const float*)d_in[2];
  const float* F    = (const float*)d_in[3];
  const float* neg  = (const float*)d_in[4];
  const int*   mask = (const int*)d_in[5];

  float* ws = (float*)d_ws;
  float* W       = ws;
  float* td      = ws + 4194304;
  float* vn2     = ws + 4202496;
  float* cb      = ws + 4210688;
  float* nn2     = ws + 4218880;
  float* fn2     = ws + 4220928;
  float* ju_part = ws + 4221440;
  float* or_part = ws + 4225536;
  float* jt_part = ws + 4225600;
  float* selc    = ws + 4225632;
  int*   seli    = (int*)(ws + 4291168);
  unsigned short* vhat_bf = (unsigned short*)(ws + 4356704);
  unsigned short* neg_bf  = vhat_bf + (size_t)B_N * D_N;
  unsigned short* F_bf    = neg_bf + (size_t)N_N * D_N;

  prep_kernel<<<(B_N + N_N + K_N) / 4, 256, 0, stream>>>(
      v, vhat, neg, F, g, vhat_bf, neg_bf, F_bf, td, vn2, cb, nn2, fn2,
      selc, seli);
  main_kernel<<<1024 + 16 + 256, 256, 0, stream>>>(
      vhat_bf, neg_bf, F_bf, cb, nn2, fn2, mask, ju_part, or_part, W);
  jt_gather_kernel<<<B_N / 256, 256, 0, stream>>>(
      seli, selc, W, fn2, mask, jt_part);
  finalize_kernel<<<1, 256, 0, stream>>>(jt_part, ju_part, or_part, mask,
                                         (float*)d_out);
}

// Round 6
// 119.262 us; speedup vs baseline: 2.7987x; 1.0591x over previous
//
#include <hip/hip_runtime.h>

// Problem constants (fixed by reference setup_inputs)
#define B_N 8192
#define D_N 256
#define N_N 2048
#define K_N 512
#define T_N 8

using short8  = __attribute__((ext_vector_type(8))) short;
using floatx4 = __attribute__((ext_vector_type(4))) float;

// ---------------------------------------------------------------------------
// Workspace layout (float units):
//  td      = ws + 0       [8192]
//  vn2     = ws + 8192    [8192]
//  cb      = ws + 16384   [8192]
//  nn2     = ws + 24576   [2048]
//  fn2     = ws + 26624   [512]
//  ju_part = ws + 27136   [4096]
//  or_part = ws + 31232   [64]
//  jt_part = ws + 31296   [1024]
//  selc    = ws + 32320   [8192*8]   (m_t + td - vn2 per selected t)
//  seli    = (int*)(ws + 97856)  [8192*8]
//  vhat_bf = (ushort*)(ws + 163392)  [8192*256]
//  neg_bf  = vhat_bf + 8192*256      [2048*256]
//  F_bf    = neg_bf + 2048*256       [512*256]
// ---------------------------------------------------------------------------

__device__ __forceinline__ float wave_reduce_sum(float x) {
  #pragma unroll
  for (int off = 32; off > 0; off >>= 1) x += __shfl_down(x, off, 64);
  return x;
}

__device__ __forceinline__ unsigned int f2bf(float x) {
  unsigned u = __float_as_uint(x);
  return (u + 0x7fffu + ((u >> 16) & 1u)) >> 16;
}

__device__ __forceinline__ unsigned int pack2bf(float x, float y) {
  return f2bf(x) | (f2bf(y) << 16);
}

// async global->LDS, 16 bytes per lane; LDS dest is wave-uniform base + lane*16
__device__ __forceinline__ void gload16(const unsigned short* g, unsigned short* l) {
  __builtin_amdgcn_global_load_lds(
      (const __attribute__((address_space(1))) unsigned int*)g,
      (__attribute__((address_space(3))) unsigned int*)l, 16, 0, 0);
}

// compare-swap keeping (val,idx) pairs together
#define CSWAP(a, b)                                              \
  {                                                              \
    bool sw_ = sv[a] > sv[b];                                    \
    float tv_ = sw_ ? sv[a] : sv[b];                             \
    sv[a] = sw_ ? sv[b] : sv[a];                                 \
    sv[b] = tv_;                                                 \
    int ti_ = sw_ ? si[a] : si[b];                               \
    si[a] = sw_ ? si[b] : si[a];                                 \
    si[b] = ti_;                                                 \
  }

// --- prep: stats + bf16 conversion + bottom-8 selection on g ----------------
// one row per wave; rows [0,B)=vhat(+v,+g-selection), [B,B+N)=neg, [B+N,..)=F
__global__ __launch_bounds__(256) void prep_kernel(
    const float* __restrict__ v, const float* __restrict__ vhat,
    const float* __restrict__ neg, const float* __restrict__ F,
    const float* __restrict__ g,
    unsigned short* __restrict__ vhat_bf, unsigned short* __restrict__ neg_bf,
    unsigned short* __restrict__ F_bf,
    float* __restrict__ td, float* __restrict__ vn2, float* __restrict__ cb,
    float* __restrict__ nn2, float* __restrict__ fn2,
    float* __restrict__ selc, int* __restrict__ seli) {
  int lane = threadIdx.x & 63;
  int row = (blockIdx.x << 2) + (threadIdx.x >> 6);
  if (row < B_N) {
    const float4 a = *(const float4*)(vhat + (size_t)row * D_N + lane * 4);
    const float4 b = *(const float4*)(v + (size_t)row * D_N + lane * 4);
    float dx = a.x - b.x, dy = a.y - b.y, dz = a.z - b.z, dw = a.w - b.w;
    float t = dx * dx + dy * dy + dz * dz + dw * dw;
    float n = a.x * a.x + a.y * a.y + a.z * a.z + a.w * a.w;
    uint2 p;
    p.x = pack2bf(a.x, a.y);
    p.y = pack2bf(a.z, a.w);
    *(uint2*)(vhat_bf + (size_t)row * D_N + lane * 4) = p;
    t = wave_reduce_sum(t);
    n = wave_reduce_sum(n);
    if (lane == 0) {
      td[row] = t;
      vn2[row] = n;
      cb[row] = 1.0f + t - n;
    }
    // ---- bottom-8-of-512 selection on g[row] ----
    const float* grow = g + (size_t)row * K_N;
    float sv[8];
    int si[8];
    {
      float4 g0 = *(const float4*)(grow + lane * 8);
      float4 g1 = *(const float4*)(grow + lane * 8 + 4);
      sv[0] = g0.x; sv[1] = g0.y; sv[2] = g0.z; sv[3] = g0.w;
      sv[4] = g1.x; sv[5] = g1.y; sv[6] = g1.z; sv[7] = g1.w;
      #pragma unroll
      for (int j = 0; j < 8; ++j) si[j] = lane * 8 + j;
    }
    // Batcher odd-even mergesort, n=8 (19 comparators) -> ascending
    CSWAP(0,1) CSWAP(2,3) CSWAP(4,5) CSWAP(6,7)
    CSWAP(0,2) CSWAP(1,3) CSWAP(4,6) CSWAP(5,7)
    CSWAP(1,2) CSWAP(5,6)
    CSWAP(0,4) CSWAP(1,5) CSWAP(2,6) CSWAP(3,7)
    CSWAP(2,4) CSWAP(3,5)
    CSWAP(1,2) CSWAP(3,4) CSWAP(5,6)
    // 6 butterfly merge rounds: keep lowest 8 of (mine ++ partner)
    #pragma unroll
    for (int rr = 0; rr < 6; ++rr) {
      const int msk = 1 << rr;
      float pv[8];
      int pi[8];
      #pragma unroll
      for (int j = 0; j < 8; ++j) {
        pv[j] = __shfl_xor(sv[j], msk, 64);
        pi[j] = __shfl_xor(si[j], msk, 64);
      }
      float cv[8];
      int ci[8];
      #pragma unroll
      for (int j = 0; j < 8; ++j) {
        bool mine = sv[j] <= pv[7 - j];
        cv[j] = mine ? sv[j] : pv[7 - j];
        ci[j] = mine ? si[j] : pi[7 - j];
      }
      #pragma unroll
      for (int j = 0; j < 8; ++j) { sv[j] = cv[j]; si[j] = ci[j]; }
      // bitonic -> sorted (distances 4,2,1)
      CSWAP(0,4) CSWAP(1,5) CSWAP(2,6) CSWAP(3,7)
      CSWAP(0,2) CSWAP(1,3) CSWAP(4,6) CSWAP(5,7)
      CSWAP(0,1) CSWAP(2,3) CSWAP(4,5) CSWAP(6,7)
    }
    // every lane now holds the global bottom-8 (sorted).
    float gsum = 1e-10f;
    #pragma unroll
    for (int t8 = 0; t8 < T_N; ++t8) gsum += sv[t8];
    if (lane == 0) {
      float base = t - n;  // td - vn2 (valid on lane 0)
      #pragma unroll
      for (int t8 = 0; t8 < T_N; ++t8) {
        float gt = sv[t8] / gsum;
        float mt = (1.0f - gt) * (1.0f - gt);
        selc[(size_t)row * T_N + t8] = mt + base;
        seli[(size_t)row * T_N + t8] = si[t8];
      }
    }
  } else if (row < B_N + N_N) {
    int r = row - B_N;
    const float4 a = *(const float4*)(neg + (size_t)r * D_N + lane * 4);
    float n = a.x * a.x + a.y * a.y + a.z * a.z + a.w * a.w;
    uint2 p;
    p.x = pack2bf(a.x, a.y);
    p.y = pack2bf(a.z, a.w);
    *(uint2*)(neg_bf + (size_t)r * D_N + lane * 4) = p;
    n = wave_reduce_sum(n);
    if (lane == 0) nn2[r] = n;
  } else {
    int r = row - (B_N + N_N);
    const float4 a = *(const float4*)(F + (size_t)r * D_N + lane * 4);
    float n = a.x * a.x + a.y * a.y + a.z * a.z + a.w * a.w;
    uint2 p;
    p.x = pack2bf(a.x, a.y);
    p.y = pack2bf(a.z, a.w);
    *(uint2*)(F_bf + (size_t)r * D_N + lane * 4) = p;
    n = wave_reduce_sum(n);
    if (lane == 0) fn2[r] = n;
  }
}

// --- main: ju tiles [0,1024) | ortho [1024,1040) | W+jt-gather [1040,1296) --
__global__ __launch_bounds__(256) void main_kernel(
    const unsigned short* __restrict__ vhat_bf, const unsigned short* __restrict__ neg_bf,
    const unsigned short* __restrict__ F_bf,
    const float* __restrict__ cb, const float* __restrict__ nn2,
    const float* __restrict__ fn2, const int* __restrict__ mask,
    const float* __restrict__ selc, const int* __restrict__ seli,
    float* __restrict__ ju_part, float* __restrict__ or_part,
    float* __restrict__ jt_part) {
  __shared__ __align__(16) unsigned char smem[16384];
  const int bx = blockIdx.x;
  const int tid = threadIdx.x;
  const int lane = tid & 63;
  const int wave = tid >> 6;

  unsigned short* AsU = (unsigned short*)smem;  // 128 rows x 32 k (bf16)
  unsigned short* BsU = AsU + 4096;
  int r0, c0;
  const unsigned short *Abase, *Bbase;
  int seg;  // 0=ju 1=ortho 2=W+jt
  if (bx < 1024) {
    seg = 0;
    r0 = (bx >> 4) * 128;
    c0 = (bx & 15) * 128;
    Abase = vhat_bf;
    Bbase = neg_bf;
  } else if (bx < 1040) {
    seg = 1;
    int o = bx - 1024;
    r0 = (o >> 2) * 128;
    c0 = (o & 3) * 128;
    Abase = F_bf;
    Bbase = F_bf;
  } else {
    seg = 2;
    int o = bx - 1040;
    r0 = (o >> 2) * 128;
    c0 = (o & 3) * 128;
    Abase = vhat_bf;
    Bbase = F_bf;
  }
  const int wx = wave & 1, wy = wave >> 1;

  // staging: LDS slot (r, c_slot) holds global 16B-chunk c_g = c_slot ^ ((r>>1)&3)
  const int c_slot = lane & 3;
  const int rA0 = wave * 32 + (lane >> 2);
  const int rA1 = rA0 + 16;
  const int cg0 = c_slot ^ ((rA0 >> 1) & 3);
  const int cg1 = c_slot ^ ((rA1 >> 1) & 3);
  const unsigned short* gA0 = Abase + (size_t)(r0 + rA0) * D_N + cg0 * 8;
  const unsigned short* gA1 = Abase + (size_t)(r0 + rA1) * D_N + cg1 * 8;
  const unsigned short* gB0 = Bbase + (size_t)(c0 + rA0) * D_N + cg0 * 8;
  const unsigned short* gB1 = Bbase + (size_t)(c0 + rA1) * D_N + cg1 * 8;
  unsigned short* lA0 = AsU + wave * 1024 + lane * 8;
  unsigned short* lA1 = lA0 + 512;
  unsigned short* lB0 = BsU + wave * 1024 + lane * 8;
  unsigned short* lB1 = lB0 + 512;

  // fragment LDS offsets (constant over k-loop)
  const int fr = lane & 15;
  const int fc = lane >> 4;
  int aoff[4], boff[4];
  #pragma unroll
  for (int i = 0; i < 4; ++i) {
    int ra = wy * 64 + i * 16 + fr;
    aoff[i] = ra * 32 + (fc ^ ((ra >> 1) & 3)) * 8;
    int rb = wx * 64 + i * 16 + fr;
    boff[i] = rb * 32 + (fc ^ ((rb >> 1) & 3)) * 8;
  }

  floatx4 acc[4][4];
  #pragma unroll
  for (int i = 0; i < 4; ++i)
    #pragma unroll
    for (int j = 0; j < 4; ++j)
      acc[i][j] = floatx4{0.0f, 0.0f, 0.0f, 0.0f};

  for (int k0 = 0; k0 < D_N; k0 += 32) {
    __syncthreads();
    gload16(gA0 + k0, lA0);
    gload16(gA1 + k0, lA1);
    gload16(gB0 + k0, lB0);
    gload16(gB1 + k0, lB1);
    __syncthreads();
    short8 af[4], bf[4];
    #pragma unroll
    for (int i = 0; i < 4; ++i) af[i] = *(const short8*)(AsU + aoff[i]);
    #pragma unroll
    for (int j = 0; j < 4; ++j) bf[j] = *(const short8*)(BsU + boff[j]);
    #pragma unroll
    for (int i = 0; i < 4; ++i)
      #pragma unroll
      for (int j = 0; j < 4; ++j)
        acc[i][j] = __builtin_amdgcn_mfma_f32_16x16x32_bf16(af[i], bf[j], acc[i][j], 0, 0, 0);
  }

  // epilogue: C/D layout col=lane&15 (j), row=(lane>>4)*4+reg (i)
  if (seg == 0) {
    float nns[4];
    #pragma unroll
    for (int j = 0; j < 4; ++j)
      nns[j] = nn2[c0 + wx * 64 + j * 16 + (lane & 15)];
    float lsum = 0.0f;
    #pragma unroll
    for (int i = 0; i < 4; ++i) {
      #pragma unroll
      for (int r = 0; r < 4; ++r) {
        int b = r0 + wy * 64 + i * 16 + (lane >> 4) * 4 + r;
        float cbb = cb[b];
        float mf = (mask[b] != 0) ? 1.0f : 0.0f;
        float rs = 0.0f;
        #pragma unroll
        for (int j = 0; j < 4; ++j) {
          float val = cbb + 2.0f * acc[i][j][r] - nns[j];
          rs += fmaxf(val, 0.0f);
        }
        lsum += mf * rs;
      }
    }
    lsum = wave_reduce_sum(lsum);
    if (lane == 0) ju_part[bx * 4 + wave] = lsum;
  } else if (seg == 1) {
    // ortho: sum (gram - I)^2; diagonal computed exactly from f32 fn2
    float lsum = 0.0f;
    #pragma unroll
    for (int i = 0; i < 4; ++i) {
      #pragma unroll
      for (int r = 0; r < 4; ++r) {
        int gi = r0 + wy * 64 + i * 16 + (lane >> 4) * 4 + r;
        #pragma unroll
        for (int j = 0; j < 4; ++j) {
          int gj = c0 + wx * 64 + j * 16 + (lane & 15);
          float s = (gi == gj) ? (fn2[gi] - 1.0f) : acc[i][j][r];
          lsum += s * s;
        }
      }
    }
    lsum = wave_reduce_sum(lsum);
    if (lane == 0) or_part[(bx - 1024) * 4 + wave] = lsum;
  } else {
    // W tile (rows r0..r0+127 of vhat x cols c0..c0+127 of F) + jt gather.
    // Spill 32x128 sub-tiles through LDS; each (b,t) jt term is owned by
    // exactly one block (the one whose col range contains seli[b][t]).
    float* Wt = (float*)smem;  // 32 x 128 f32 = 16 KB
    const int quad = lane >> 4, col15 = lane & 15;
    const int rl = tid >> 3;   // 0..31
    const int t8 = tid & 7;    // 0..7
    float jts = 0.0f;
    #pragma unroll
    for (int i = 0; i < 4; ++i) {
      __syncthreads();  // protect smem reuse (GEMM frags / previous pass)
      #pragma unroll
      for (int r = 0; r < 4; ++r) {
        int row_local = wy * 16 + quad * 4 + r;
        #pragma unroll
        for (int j = 0; j < 4; ++j)
          Wt[row_local * 128 + wx * 64 + j * 16 + col15] = acc[i][j][r];
      }
      __syncthreads();
      // 256 (row,t) lookups for the 32 rows in this pass
      int b = r0 + (rl & 15) + i * 16 + (rl >> 4) * 64;
      int idx = seli[(size_t)b * 8 + t8];
      int c = idx - c0;
      if ((unsigned)c < 128u) {
        float w = Wt[rl * 128 + c];
        float term = selc[(size_t)b * 8 + t8] + 2.0f * w - fn2[idx];
        float mf = (mask[b] != 0) ? 1.0f : 0.0f;
        jts += mf * fmaxf(term, 0.0f);
      }
    }
    jts = wave_reduce_sum(jts);
    if (lane == 0) jt_part[(bx - 1040) * 4 + wave] = jts;
  }
}

// --- finalize: sum partial arrays + msum, compute output --------------------
__global__ __launch_bounds__(256) void finalize_kernel(
    const float* __restrict__ jt_part, const float* __restrict__ ju_part,
    const float* __restrict__ or_part, const int* __restrict__ mask,
    float* __restrict__ out) {
  int tid = threadIdx.x;
  float sjt = 0.0f, sju = 0.0f, sor = 0.0f, sm = 0.0f;
  for (int i = tid; i < B_N; i += 256) sm += (mask[i] != 0) ? 1.0f : 0.0f;
  for (int i = tid; i < 4096; i += 256) sju += ju_part[i];
  for (int i = tid; i < 1024; i += 256) sjt += jt_part[i];
  if (tid < 64) sor = or_part[tid];
  sjt = wave_reduce_sum(sjt);
  sju = wave_reduce_sum(sju);
  sor = wave_reduce_sum(sor);
  sm  = wave_reduce_sum(sm);
  __shared__ float red[4][4];
  int lane = tid & 63, w = tid >> 6;
  if (lane == 0) {
    red[w][0] = sjt; red[w][1] = sju; red[w][2] = sor; red[w][3] = sm;
  }
  __syncthreads();
  if (tid == 0) {
    float jt = red[0][0] + red[1][0] + red[2][0] + red[3][0];
    float ju = red[0][1] + red[1][1] + red[2][1] + red[3][1];
    float oo = red[0][2] + red[1][2] + red[2][2] + red[3][2];
    float ms = red[0][3] + red[1][3] + red[2][3] + red[3][3];
    float Ju = (ms == 0.0f) ? 0.0f : ju / ((float)N_N * ms);
    float Jt = (ms == 0.0f) ? 0.0f : jt / ms;
    out[0] = Ju + Jt + 1.0e-3f * oo;
  }
}

extern "C" void kernel_launch(void* const* d_in, const int* in_sizes, int n_in,
                              void* d_out, int out_size, void* d_ws, size_t ws_size,
                              hipStream_t stream) {
  (void)in_sizes; (void)n_in; (void)out_size; (void)ws_size;
  const float* v    = (const float*)d_in[0];
  const float* vhat = (const float*)d_in[1];
  const float* g    = (const float*)d_in[2];
  const float* F    = (const float*)d_in[3];
  const float* neg  = (const float*)d_in[4];
  const int*   mask = (const int*)d_in[5];

  float* ws = (float*)d_ws;
  float* td      = ws;
  float* vn2     = ws + 8192;
  float* cb      = ws + 16384;
  float* nn2     = ws + 24576;
  float* fn2     = ws + 26624;
  float* ju_part = ws + 27136;
  float* or_part = ws + 31232;
  float* jt_part = ws + 31296;
  float* selc    = ws + 32320;
  int*   seli    = (int*)(ws + 97856);
  unsigned short* vhat_bf = (unsigned short*)(ws + 163392);
  unsigned short* neg_bf  = vhat_bf + (size_t)B_N * D_N;
  unsigned short* F_bf    = neg_bf + (size_t)N_N * D_N;

  prep_kernel<<<(B_N + N_N + K_N) / 4, 256, 0, stream>>>(
      v, vhat, neg, F, g, vhat_bf, neg_bf, F_bf, td, vn2, cb, nn2, fn2,
      selc, seli);
  main_kernel<<<1024 + 16 + 256, 256, 0, stream>>>(
      vhat_bf, neg_bf, F_bf, cb, nn2, fn2, mask, selc, seli,
      ju_part, or_part, jt_part);
  finalize_kernel<<<1, 256, 0, stream>>>(jt_part, ju_part, or_part, mask,
                                         (float*)d_out);
}